// Round 13
// baseline (241.628 us; speedup 1.0000x reference)
//
#include <hip/hip_runtime.h>
#include <math.h>

// MaskedMultiHeadAttention (B=4, L=2048, D=1024), fp32 in/out, fp16-MFMA internals.
// d_out = [ out : 4*2048*1024 f32 | attn : 4*2048*2048 f32 ]
// ws (92MB): wq wk wv wo (f16) | qh | kh | vT | attn16 (f16); x reuses qh.
// Round 13: proj_qkv ported to the proven 8-wave 256x256 BK=32 quad-buffered
// counted-vmcnt pipeline (same structure as hgemm8_scores, round-12, +15us).
// PV / out-proj stay classic: at 256^2 tiles they'd get 128 blocks = 0.5/CU.

static constexpr int B_ = 4;
static constexpr int L_ = 2048;
static constexpr int D_ = 1024;

#define BM 128
#define BN 128
#define BKK 64   // K-step in elements (fp16) for the classic kernels

typedef _Float16 f16x8 __attribute__((ext_vector_type(8)));
typedef float    f32x4 __attribute__((ext_vector_type(4)));
typedef short    s16x8 __attribute__((ext_vector_type(8)));
typedef unsigned short u16x4 __attribute__((ext_vector_type(4)));

typedef __attribute__((address_space(1))) const unsigned int GU32;
typedef __attribute__((address_space(3))) unsigned int LU32;

__device__ __forceinline__ void gload_lds16(const void* g, void* l) {
    __builtin_amdgcn_global_load_lds((GU32*)g, (LU32*)l, 16, 0, 0);
}

__device__ __forceinline__ short f2h_bits(float x) {
    union { _Float16 h; short s; } u;
    u.h = (_Float16)x;
    return u.s;
}

__device__ __forceinline__ s16x8 cvt8h(float4 a, float4 b) {
    union { _Float16 h[8]; s16x8 s; } u;
    u.h[0] = (_Float16)a.x; u.h[1] = (_Float16)a.y;
    u.h[2] = (_Float16)a.z; u.h[3] = (_Float16)a.w;
    u.h[4] = (_Float16)b.x; u.h[5] = (_Float16)b.y;
    u.h[6] = (_Float16)b.z; u.h[7] = (_Float16)b.w;
    return u.s;
}

// ================= classic 128x128 kernels (proven) =================

__device__ __forceinline__ void compute_step(
    const short* __restrict__ As, const short* __restrict__ Bs,
    int wr, int wc, int lr, int lk, f32x4 (&acc)[4][4])
{
#pragma unroll
    for (int kk = 0; kk < 2; ++kk) {
        const int slotk = kk * 4 + lk;
        f16x8 a[4], b[4];
#pragma unroll
        for (int m = 0; m < 4; ++m) {
            const int r = wr * 64 + m * 16 + lr;
            a[m] = *(const f16x8*)&As[r * 64 + ((slotk ^ (r & 7)) << 3)];
        }
#pragma unroll
        for (int n = 0; n < 4; ++n) {
            const int c = wc * 64 + n * 16 + lr;
            b[n] = *(const f16x8*)&Bs[c * 64 + ((slotk ^ (c & 7)) << 3)];
        }
#pragma unroll
        for (int m = 0; m < 4; ++m)
#pragma unroll
            for (int n = 0; n < 4; ++n)
                acc[m][n] = __builtin_amdgcn_mfma_f32_16x16x32_f16(a[m], b[n], acc[m][n], 0, 0, 0);
    }
}

template<int APPLY_SM>
__device__ __forceinline__ void epilogue_f16_bounce(
    short* __restrict__ lw, short* __restrict__ C, long N,
    int bm, int bn, int wr, int wc, int lr, int lk, int lane,
    const f32x4 (&acc)[4][4], float scale, bool msk)
{
#pragma unroll
    for (int m = 0; m < 4; ++m) {
        const int rl0 = m * 16 + lk * 4;
#pragma unroll
        for (int n = 0; n < 4; ++n) {
            const int cl = n * 16 + lr;
            const int slot = cl >> 3, cw = cl & 7;
#pragma unroll
            for (int g = 0; g < 4; ++g) {
                const int rl = rl0 + g;
                float v = acc[m][n][g];
                if constexpr (APPLY_SM) {
                    v *= scale;
                    if (msk && (bn + wc * 64 + cl) <= (bm + wr * 64 + rl)) v = -INFINITY;
                }
                lw[rl * 64 + ((slot ^ (rl & 7)) << 3) + cw] = f2h_bits(v);
            }
        }
    }
    const int l8 = lane & 7, lr8 = lane >> 3;
#pragma unroll
    for (int it = 0; it < 8; ++it) {
        const int rl = it * 8 + lr8;
        const int cl = (l8 ^ (rl & 7)) << 3;
        s16x8 d = *(const s16x8*)&lw[rl * 64 + (l8 << 3)];
        *(s16x8*)&C[(long)(bm + wr * 64 + rl) * N + bn + wc * 64 + cl] = d;
    }
}

// generic f16 GEMM. OMODE: 0 = f16 [M,N]; 2 = f32 (out-proj).
template<int OMODE>
__global__ __launch_bounds__(256) void hgemm(
    const short* __restrict__ A16p, const short* __restrict__ Btp, void* __restrict__ Cp_,
    int M, int N, int K, long sA, long sB, long sC,
    float scale, int useMask, const int* __restrict__ mflag)
{
    __shared__ short smem[2 * BM * BKK];
    short* As = smem;
    short* Bs = smem + BM * BKK;

    const int t    = threadIdx.x;
    const int wid  = t >> 6;
    const int lane = t & 63;
    const int bz   = blockIdx.z;

    const int gx = gridDim.x, gy = gridDim.y;
    const int wg = blockIdx.y * gx + blockIdx.x;
    const int bm = (wg % gy) * BM;
    const int bn = (wg / gy) * BN;

    const short* Bt  = Btp + (long)bz * sB;
    const short* A16 = A16p + (long)bz * sA;

    const int wr = wid >> 1, wc = wid & 1;
    const int lr = lane & 15, lk = lane >> 4;
    const int srow = t >> 3, sslot = t & 7;

    f32x4 acc[4][4];
#pragma unroll
    for (int m = 0; m < 4; ++m)
#pragma unroll
        for (int n = 0; n < 4; ++n) acc[m][n] = (f32x4)0.f;

    for (int k0 = 0; k0 < K; k0 += BKK) {
        __syncthreads();
#pragma unroll
        for (int i = 0; i < 4; ++i) {
            const int rb = i * 32 + srow;
            const short* g = Bt + (long)(bn + rb) * K + k0 + ((sslot ^ (rb & 7)) << 3);
            gload_lds16(g, &Bs[i * 2048 + wid * 512]);
        }
#pragma unroll
        for (int i = 0; i < 4; ++i) {
            const int ra = i * 32 + srow;
            const short* g = A16 + (long)(bm + ra) * K + k0 + ((sslot ^ (ra & 7)) << 3);
            gload_lds16(g, &As[i * 2048 + wid * 512]);
        }
        __syncthreads();
        compute_step(As, Bs, wr, wc, lr, lk, acc);
    }

    if constexpr (OMODE == 2) {
        float* C = (float*)Cp_ + (long)bz * sC;
#pragma unroll
        for (int m = 0; m < 4; ++m) {
            const int r0 = bm + wr * 64 + m * 16 + lk * 4;
#pragma unroll
            for (int n = 0; n < 4; ++n) {
                const int c = bn + wc * 64 + n * 16 + lr;
#pragma unroll
                for (int g = 0; g < 4; ++g)
                    C[(long)(r0 + g) * N + c] = acc[m][n][g] * scale;
            }
        }
    } else {
        __syncthreads();
        short* C = (short*)Cp_ + (long)bz * sC;
        epilogue_f16_bounce<0>(smem + wid * 4096, C, N, bm, bn, wr, wc, lr, lk, lane,
                               acc, scale, false);
    }
}

// ================= 8-wave deep-pipelined GEMMs =================
// 256x256 tile, BK=32, quad-buffered LDS (128KB), depth-3 prefetch,
// counted vmcnt gate (8/4/0) + ONE raw s_barrier per K-step.

__device__ __forceinline__ void stage8(
    const short* __restrict__ A16, const short* __restrict__ Bt,
    short* __restrict__ As, short* __restrict__ Bs,
    int bm, int bn, int k0, int K, int t, int wid)
{
    const int r0 = t >> 2;    // 0..127 (source row within 128-row chunk)
    const int sl = t & 3;     // 16B slot 0..3
#pragma unroll
    for (int i = 0; i < 2; ++i) {
        const int r = i * 128 + r0;
        const short* g = A16 + (long)(bm + r) * K + k0 + ((sl ^ ((r >> 1) & 3)) << 3);
        gload_lds16(g, As + i * 4096 + wid * 512);
    }
#pragma unroll
    for (int i = 0; i < 2; ++i) {
        const int r = i * 128 + r0;
        const short* g = Bt + (long)(bn + r) * K + k0 + ((sl ^ ((r >> 1) & 3)) << 3);
        gload_lds16(g, Bs + i * 4096 + wid * 512);
    }
}

__device__ __forceinline__ void compute32(
    const short* __restrict__ As, const short* __restrict__ Bs,
    int wr, int wc, int lr, int lk, f32x4 (&acc)[8][4])
{
    f16x8 a[8], b[4];
#pragma unroll
    for (int m = 0; m < 8; ++m) {
        const int r = wr * 128 + m * 16 + lr;
        a[m] = *(const f16x8*)&As[r * 32 + ((lk ^ ((r >> 1) & 3)) << 3)];
    }
#pragma unroll
    for (int n = 0; n < 4; ++n) {
        const int c = wc * 64 + n * 16 + lr;
        b[n] = *(const f16x8*)&Bs[c * 32 + ((lk ^ ((c >> 1) & 3)) << 3)];
    }
    __builtin_amdgcn_s_setprio(1);
#pragma unroll
    for (int m = 0; m < 8; ++m)
#pragma unroll
        for (int n = 0; n < 4; ++n)
            acc[m][n] = __builtin_amdgcn_mfma_f32_16x16x32_f16(a[m], b[n], acc[m][n], 0, 0, 0);
    __builtin_amdgcn_s_setprio(0);
}

template<int APPLY_SM>
__device__ __forceinline__ void epilogue_f16_bounce8(
    short* __restrict__ lw, short* __restrict__ C, long N,
    int rowBase, int colBase, int lr, int lk, int lane,
    const f32x4 (&acc)[8][4], float scale, bool msk)
{
#pragma unroll
    for (int h = 0; h < 2; ++h) {
#pragma unroll
        for (int mm = 0; mm < 4; ++mm) {
            const int m = h * 4 + mm;
            const int rl0 = mm * 16 + lk * 4;
#pragma unroll
            for (int n = 0; n < 4; ++n) {
                const int cl = n * 16 + lr;
                const int slot = cl >> 3, cw = cl & 7;
#pragma unroll
                for (int g = 0; g < 4; ++g) {
                    const int rl = rl0 + g;
                    float v = acc[m][n][g];
                    if constexpr (APPLY_SM) {
                        v *= scale;
                        if (msk && (colBase + cl) <= (rowBase + h * 64 + rl)) v = -INFINITY;
                    }
                    lw[rl * 64 + ((slot ^ (rl & 7)) << 3) + cw] = f2h_bits(v);
                }
            }
        }
        const int l8 = lane & 7, lr8 = lane >> 3;
#pragma unroll
        for (int it = 0; it < 8; ++it) {
            const int rl = it * 8 + lr8;
            const int cl = (l8 ^ (rl & 7)) << 3;
            s16x8 d = *(const s16x8*)&lw[rl * 64 + (l8 << 3)];
            *(s16x8*)&C[(long)(rowBase + h * 64 + rl) * N + colBase + cl] = d;
        }
    }
}

// The shared K-loop pipeline: prologue(3 tiles) + counted-vmcnt steady state.
__device__ __forceinline__ void pipeline_loop(
    const short* __restrict__ A16, const short* __restrict__ Bt,
    short* __restrict__ Abuf, short* __restrict__ Bbuf,
    int bm, int bn, int K, int t, int wid,
    int wr, int wc, int lr, int lk, f32x4 (&acc)[8][4])
{
    stage8(A16, Bt, Abuf + 0 * 8192, Bbuf + 0 * 8192, bm, bn, 0,  K, t, wid);
    stage8(A16, Bt, Abuf + 1 * 8192, Bbuf + 1 * 8192, bm, bn, 32, K, t, wid);
    stage8(A16, Bt, Abuf + 2 * 8192, Bbuf + 2 * 8192, bm, bn, 64, K, t, wid);

    const int nt = K / 32;
    for (int ti = 0; ti < nt; ++ti) {
        if (ti + 2 < nt)      asm volatile("s_waitcnt vmcnt(8)" ::: "memory");
        else if (ti + 1 < nt) asm volatile("s_waitcnt vmcnt(4)" ::: "memory");
        else                  asm volatile("s_waitcnt vmcnt(0)" ::: "memory");
        __builtin_amdgcn_sched_barrier(0);
        __builtin_amdgcn_s_barrier();
        __builtin_amdgcn_sched_barrier(0);
        asm volatile("" ::: "memory");
        if (ti + 3 < nt) {
            const int nb = (ti + 3) & 3;
            stage8(A16, Bt, Abuf + nb * 8192, Bbuf + nb * 8192, bm, bn,
                   (ti + 3) * 32, K, t, wid);
        }
        const int cb = ti & 3;
        compute32(Abuf + cb * 8192, Bbuf + cb * 8192, wr, wc, lr, lk, acc);
    }
    __syncthreads();   // all buffer reads done before LDS reuse by epilogue
}

// scores = qh @ kh^T * 0.125 -> f16 attn16 (+ faithful-buggy tril mask)
// grid (8, 8, 4), 512 threads, K=1024.
__global__ __launch_bounds__(512) void hgemm8_scores(
    const short* __restrict__ qhp, const short* __restrict__ khp,
    short* __restrict__ Cp, const int* __restrict__ mflag)
{
    __shared__ short smem[65536];   // A: 4 x 16KB | B: 4 x 16KB = 128 KB

    const int t    = threadIdx.x;
    const int wid  = t >> 6;
    const int lane = t & 63;
    const int bz   = blockIdx.z;
    const int K    = D_;

    const int wg = blockIdx.y * 8 + blockIdx.x;
    const int bm = (wg % 8) * 256;
    const int bn = (wg / 8) * 256;

    const short* A16 = qhp + (long)bz * L_ * D_;
    const short* Bt  = khp + (long)bz * L_ * D_;
    short* C = Cp + (long)bz * ((long)L_ * L_);

    const int wr = wid >> 2, wc = wid & 3;
    const int lr = lane & 15, lk = lane >> 4;

    f32x4 acc[8][4];
#pragma unroll
    for (int m = 0; m < 8; ++m)
#pragma unroll
        for (int n = 0; n < 4; ++n) acc[m][n] = (f32x4)0.f;

    pipeline_loop(A16, Bt, smem, smem + 32768, bm, bn, K, t, wid, wr, wc, lr, lk, acc);

    const bool msk = (mflag[0] != 0);
    epilogue_f16_bounce8<1>(smem + wid * 4096, C, L_,
                            bm + wr * 128, bn + wc * 64, lr, lk, lane,
                            acc, 0.125f, msk);
}

// fused QKV projections, deep pipeline. grid (4, 32, 3), 512 threads.
// z=0: qh = qf@wq^T; z=1: kh = kf@wk^T; z=2: vT[b][col][row] = vf@wv^T.
__global__ __launch_bounds__(512) void hgemm8_proj(
    const short* __restrict__ qf, const short* __restrict__ kf, const short* __restrict__ vf,
    const short* __restrict__ wq, const short* __restrict__ wk, const short* __restrict__ wv,
    short* __restrict__ qh, short* __restrict__ kh, short* __restrict__ vT)
{
    __shared__ short smem[65536];

    const int t    = threadIdx.x;
    const int wid  = t >> 6;
    const int lane = t & 63;
    const int bz   = blockIdx.z;
    const int K    = D_;
    const int N    = D_;

    const short* A16 = (bz == 0) ? qf : (bz == 1) ? kf : vf;
    const short* Bt  = (bz == 0) ? wq : (bz == 1) ? wk : wv;

    const int wg = blockIdx.y * 4 + blockIdx.x;   // 0..127
    const int bm = (wg & 31) * 256;               // M-panel pinned to one XCD
    const int bn = (wg >> 5) * 256;

    const int wr = wid >> 2, wc = wid & 3;
    const int lr = lane & 15, lk = lane >> 4;

    f32x4 acc[8][4];
#pragma unroll
    for (int m = 0; m < 8; ++m)
#pragma unroll
        for (int n = 0; n < 4; ++n) acc[m][n] = (f32x4)0.f;

    pipeline_loop(A16, Bt, smem, smem + 32768, bm, bn, K, t, wid, wr, wc, lr, lk, acc);

    if (bz < 2) {
        short* C = (bz == 0) ? qh : kh;
        epilogue_f16_bounce8<0>(smem + wid * 4096, C, N,
                                bm + wr * 128, bn + wc * 64, lr, lk, lane,
                                acc, 1.f, false);
    } else {
#pragma unroll
        for (int m = 0; m < 8; ++m) {
            const int rg = bm + wr * 128 + m * 16 + lk * 4;
            const long rb = (long)(rg >> 11) * ((long)N * L_) + (rg & (L_ - 1));
#pragma unroll
            for (int n = 0; n < 4; ++n) {
                const int c = bn + wc * 64 + n * 16 + lr;
                u16x4 v;
#pragma unroll
                for (int g = 0; g < 4; ++g) v[g] = (unsigned short)f2h_bits(acc[m][n][g]);
                *(u16x4*)&vT[rb + (long)c * L_] = v;
            }
        }
    }
}

// ================= small kernels (proven) =================

__global__ __launch_bounds__(256) void cvt_w4_k(
    const float* __restrict__ W_Q, const float* __restrict__ W_K,
    const float* __restrict__ W_V, const float* __restrict__ W_O,
    short* __restrict__ dst)
{
    const int w = blockIdx.y;
    const float* src = (w == 0) ? W_Q : (w == 1) ? W_K : (w == 2) ? W_V : W_O;
    short* out = dst + (size_t)w * D_ * D_;
    const int i = blockIdx.x * 256 + threadIdx.x;
    float4 a = ((const float4*)src)[2 * i];
    float4 b = ((const float4*)src)[2 * i + 1];
    *(s16x8*)&out[i * 8] = cvt8h(a, b);
}

__global__ __launch_bounds__(256) void cvt_qkv_k(
    const float* __restrict__ Q, const float* __restrict__ K,
    const float* __restrict__ V, short* __restrict__ dst)
{
    const int w = blockIdx.y;
    const float* src = (w == 0) ? Q : (w == 1) ? K : V;
    short* out = dst + (size_t)w * B_ * L_ * D_;
    const int i = blockIdx.x * 256 + threadIdx.x;
    float4 a = ((const float4*)src)[2 * i];
    float4 b = ((const float4*)src)[2 * i + 1];
    *(s16x8*)&out[i * 8] = cvt8h(a, b);
}

// row softmax over f16 unnormalized scores (rows of 2048):
// writes fp32 normalized attn (d_out) + f16 normalized copy in place.
__global__ __launch_bounds__(256) void softmax_rows_k(
    short* __restrict__ S16, float* __restrict__ Sout)
{
    const long row = blockIdx.x;
    short* p16 = S16 + row * (long)L_;
    float* pf  = Sout + row * (long)L_;
    const int tid = threadIdx.x;

    union { s16x8 v; _Float16 h[8]; } u;
    u.v = ((const s16x8*)p16)[tid];
    float f[8];
#pragma unroll
    for (int j = 0; j < 8; ++j) f[j] = (float)u.h[j];

    float m = f[0];
#pragma unroll
    for (int j = 1; j < 8; ++j) m = fmaxf(m, f[j]);
#pragma unroll
    for (int o = 32; o > 0; o >>= 1) m = fmaxf(m, __shfl_xor(m, o, 64));

    __shared__ float wmax[4], wsum[4];
    if ((tid & 63) == 0) wmax[tid >> 6] = m;
    __syncthreads();
    m = fmaxf(fmaxf(wmax[0], wmax[1]), fmaxf(wmax[2], wmax[3]));

    float s = 0.f;
#pragma unroll
    for (int j = 0; j < 8; ++j) { f[j] = expf(f[j] - m); s += f[j]; }
#pragma unroll
    for (int o = 32; o > 0; o >>= 1) s += __shfl_xor(s, o, 64);
    if ((tid & 63) == 0) wsum[tid >> 6] = s;
    __syncthreads();
    s = wsum[0] + wsum[1] + wsum[2] + wsum[3];

    const float inv = 1.f / s;
#pragma unroll
    for (int j = 0; j < 8; ++j) f[j] = f[j] * inv;

    float4 a, b;
    a.x = f[0]; a.y = f[1]; a.z = f[2]; a.w = f[3];
    b.x = f[4]; b.y = f[5]; b.z = f[6]; b.w = f[7];
    ((float4*)pf)[2 * tid]     = a;
    ((float4*)pf)[2 * tid + 1] = b;
    ((s16x8*)p16)[tid] = cvt8h(a, b);
}

extern "C" void kernel_launch(void* const* d_in, const int* in_sizes, int n_in,
                              void* d_out, int out_size, void* d_ws, size_t ws_size,
                              hipStream_t stream) {
    const float* Q   = (const float*)d_in[0];
    const float* K   = (const float*)d_in[1];
    const float* V   = (const float*)d_in[2];
    const float* W_Q = (const float*)d_in[3];
    const float* W_K = (const float*)d_in[4];
    const float* W_V = (const float*)d_in[5];
    const float* W_O = (const float*)d_in[6];
    const int* masked = (const int*)d_in[7];

    float* out  = (float*)d_out;                    // [4,2048,1024]
    float* attn = out + (size_t)B_ * L_ * D_;       // [4,2048,2048]

    // ws layout (shorts): 8MB weights | qh 16.8 | kh 16.8 | vT 16.8 | attn16 33.6
    short* wq = (short*)d_ws;
    short* wk = wq + (size_t)D_ * D_;
    short* wv = wk + (size_t)D_ * D_;
    short* wo = wv + (size_t)D_ * D_;
    short* qh = wo + (size_t)D_ * D_;               // [8192,1024] f16
    short* kh = qh + (size_t)B_ * L_ * D_;
    short* vT = kh + (size_t)B_ * L_ * D_;          // [4][1024][2048] f16
    short* attn16 = vT + (size_t)B_ * L_ * D_;      // [4][2048][2048] f16
    short* xh = qh;                                 // reuse after scores

    // fp16 Q/K/V copies live in d_out's attn region (dead before softmax writes it)
    short* qf = (short*)attn;                       // 3 x 16.8 MB <= 67 MB
    short* kf = qf + (size_t)B_ * L_ * D_;
    short* vf = kf + (size_t)B_ * L_ * D_;

    const long SLD = (long)L_ * D_;
    const long SLL = (long)L_ * L_;

    // 1) weights + inputs fp32 -> fp16
    cvt_w4_k<<<dim3(D_ * D_ / 8 / 256, 4), 256, 0, stream>>>(W_Q, W_K, W_V, W_O, wq);
    cvt_qkv_k<<<dim3(B_ * L_ * D_ / 8 / 256, 3), 256, 0, stream>>>(Q, K, V, qf);

    // 2) fused QKV projections: deep pipeline, 384 blocks
    hgemm8_proj<<<dim3(4, 32, 3), 512, 0, stream>>>(
        qf, kf, vf, wq, wk, wv, qh, kh, vT);

    // 3) scores = q @ k^T / 8 -> f16 UNNORMALIZED into attn16 (+ faithful mask)
    hgemm8_scores<<<dim3(8, 8, B_), 512, 0, stream>>>(qh, kh, attn16, masked);

    // 4) softmax rows: read f16 scores, write fp32 attn + normalized f16 in place
    softmax_rows_k<<<dim3(B_ * L_), 256, 0, stream>>>(attn16, attn);

    // 5) x = attn16 @ vT -> f16 x
    dim3 gav(D_ / BN, L_ / BM, B_);                 // gy=16
    hgemm<0><<<gav, 256, 0, stream>>>(attn16, vT, xh, L_, D_, L_, SLL, SLD, SLD,
                                      1.f, 0, masked);

    // 6) out = x @ W_O^T -> fp32
    dim3 gproj(D_ / BN, (B_ * L_) / BM, 1);         // gy=64
    hgemm<2><<<gproj, 256, 0, stream>>>(xh, wo, out, B_ * L_, D_, D_, 0, 0, 0,
                                        1.f, 0, masked);
}

// Round 15
// 236.882 us; speedup vs baseline: 1.0200x; 1.0200x over previous
//
#include <hip/hip_runtime.h>
#include <math.h>

// MaskedMultiHeadAttention (B=4, L=2048, D=1024), fp32 in/out, fp16-MFMA internals.
// d_out = [ out : 4*2048*1024 f32 | attn : 4*2048*2048 f32 ]
// ws (92MB): wq wk wv wo (f16) | qh | kh | vT | attn16 (f16); x reuses qh.
// Round 15 = round 14 with stage4 geometry FIXED: wave spacing 512 shorts
// (64 lanes x 16B), chunk 2048, buffer 4096 shorts (8KB), total LDS 64KB.
// Round-14's stage4 copied 8-wave spacing -> half of each tile unwritten -> NaN.

static constexpr int B_ = 4;
static constexpr int L_ = 2048;
static constexpr int D_ = 1024;

typedef _Float16 f16x8 __attribute__((ext_vector_type(8)));
typedef float    f32x4 __attribute__((ext_vector_type(4)));
typedef short    s16x8 __attribute__((ext_vector_type(8)));
typedef unsigned short u16x4 __attribute__((ext_vector_type(4)));

typedef __attribute__((address_space(1))) const unsigned int GU32;
typedef __attribute__((address_space(3))) unsigned int LU32;

__device__ __forceinline__ void gload_lds16(const void* g, void* l) {
    __builtin_amdgcn_global_load_lds((GU32*)g, (LU32*)l, 16, 0, 0);
}

__device__ __forceinline__ short f2h_bits(float x) {
    union { _Float16 h; short s; } u;
    u.h = (_Float16)x;
    return u.s;
}

__device__ __forceinline__ s16x8 cvt8h(float4 a, float4 b) {
    union { _Float16 h[8]; s16x8 s; } u;
    u.h[0] = (_Float16)a.x; u.h[1] = (_Float16)a.y;
    u.h[2] = (_Float16)a.z; u.h[3] = (_Float16)a.w;
    u.h[4] = (_Float16)b.x; u.h[5] = (_Float16)b.y;
    u.h[6] = (_Float16)b.z; u.h[7] = (_Float16)b.w;
    return u.s;
}

// ============== 8-wave 256x256 pipeline (round-12 proven, scores only) ==============

__device__ __forceinline__ void stage8(
    const short* __restrict__ A16, const short* __restrict__ Bt,
    short* __restrict__ As, short* __restrict__ Bs,
    int bm, int bn, int k0, int K, int t, int wid)
{
    const int r0 = t >> 2;
    const int sl = t & 3;
#pragma unroll
    for (int i = 0; i < 2; ++i) {
        const int r = i * 128 + r0;
        const short* g = A16 + (long)(bm + r) * K + k0 + ((sl ^ ((r >> 1) & 3)) << 3);
        gload_lds16(g, As + i * 4096 + wid * 512);
    }
#pragma unroll
    for (int i = 0; i < 2; ++i) {
        const int r = i * 128 + r0;
        const short* g = Bt + (long)(bn + r) * K + k0 + ((sl ^ ((r >> 1) & 3)) << 3);
        gload_lds16(g, Bs + i * 4096 + wid * 512);
    }
}

__device__ __forceinline__ void compute32_w8(
    const short* __restrict__ As, const short* __restrict__ Bs,
    int wr, int wc, int lr, int lk, f32x4 (&acc)[8][4])
{
    f16x8 a[8], b[4];
#pragma unroll
    for (int m = 0; m < 8; ++m) {
        const int r = wr * 128 + m * 16 + lr;
        a[m] = *(const f16x8*)&As[r * 32 + ((lk ^ ((r >> 1) & 3)) << 3)];
    }
#pragma unroll
    for (int n = 0; n < 4; ++n) {
        const int c = wc * 64 + n * 16 + lr;
        b[n] = *(const f16x8*)&Bs[c * 32 + ((lk ^ ((c >> 1) & 3)) << 3)];
    }
    __builtin_amdgcn_s_setprio(1);
#pragma unroll
    for (int m = 0; m < 8; ++m)
#pragma unroll
        for (int n = 0; n < 4; ++n)
            acc[m][n] = __builtin_amdgcn_mfma_f32_16x16x32_f16(a[m], b[n], acc[m][n], 0, 0, 0);
    __builtin_amdgcn_s_setprio(0);
}

template<int APPLY_SM>
__device__ __forceinline__ void epilogue_f16_bounce8(
    short* __restrict__ lw, short* __restrict__ C, long N,
    int rowBase, int colBase, int lr, int lk, int lane,
    const f32x4 (&acc)[8][4], float scale, bool msk)
{
#pragma unroll
    for (int h = 0; h < 2; ++h) {
#pragma unroll
        for (int mm = 0; mm < 4; ++mm) {
            const int m = h * 4 + mm;
            const int rl0 = mm * 16 + lk * 4;
#pragma unroll
            for (int n = 0; n < 4; ++n) {
                const int cl = n * 16 + lr;
                const int slot = cl >> 3, cw = cl & 7;
#pragma unroll
                for (int g = 0; g < 4; ++g) {
                    const int rl = rl0 + g;
                    float v = acc[m][n][g];
                    if constexpr (APPLY_SM) {
                        v *= scale;
                        if (msk && (colBase + cl) <= (rowBase + h * 64 + rl)) v = -INFINITY;
                    }
                    lw[rl * 64 + ((slot ^ (rl & 7)) << 3) + cw] = f2h_bits(v);
                }
            }
        }
        const int l8 = lane & 7, lr8 = lane >> 3;
#pragma unroll
        for (int it = 0; it < 8; ++it) {
            const int rl = it * 8 + lr8;
            const int cl = (l8 ^ (rl & 7)) << 3;
            s16x8 d = *(const s16x8*)&lw[rl * 64 + (l8 << 3)];
            *(s16x8*)&C[(long)(rowBase + h * 64 + rl) * N + colBase + cl] = d;
        }
    }
}

__device__ __forceinline__ void pipeline_loop8(
    const short* __restrict__ A16, const short* __restrict__ Bt,
    short* __restrict__ Abuf, short* __restrict__ Bbuf,
    int bm, int bn, int K, int t, int wid,
    int wr, int wc, int lr, int lk, f32x4 (&acc)[8][4])
{
    stage8(A16, Bt, Abuf + 0 * 8192, Bbuf + 0 * 8192, bm, bn, 0,  K, t, wid);
    stage8(A16, Bt, Abuf + 1 * 8192, Bbuf + 1 * 8192, bm, bn, 32, K, t, wid);
    stage8(A16, Bt, Abuf + 2 * 8192, Bbuf + 2 * 8192, bm, bn, 64, K, t, wid);

    const int nt = K / 32;
    for (int ti = 0; ti < nt; ++ti) {
        if (ti + 2 < nt)      asm volatile("s_waitcnt vmcnt(8)" ::: "memory");
        else if (ti + 1 < nt) asm volatile("s_waitcnt vmcnt(4)" ::: "memory");
        else                  asm volatile("s_waitcnt vmcnt(0)" ::: "memory");
        __builtin_amdgcn_sched_barrier(0);
        __builtin_amdgcn_s_barrier();
        __builtin_amdgcn_sched_barrier(0);
        asm volatile("" ::: "memory");
        if (ti + 3 < nt) {
            const int nb = (ti + 3) & 3;
            stage8(A16, Bt, Abuf + nb * 8192, Bbuf + nb * 8192, bm, bn,
                   (ti + 3) * 32, K, t, wid);
        }
        const int cb = ti & 3;
        compute32_w8(Abuf + cb * 8192, Bbuf + cb * 8192, wr, wc, lr, lk, acc);
    }
    __syncthreads();
}

// scores = qh @ kh^T * 0.125 -> f16 attn16 (+ faithful-buggy tril mask)
__global__ __launch_bounds__(512) void hgemm8_scores(
    const short* __restrict__ qhp, const short* __restrict__ khp,
    short* __restrict__ Cp, const int* __restrict__ mflag)
{
    __shared__ short smem[65536];

    const int t    = threadIdx.x;
    const int wid  = t >> 6;
    const int lane = t & 63;
    const int bz   = blockIdx.z;
    const int K    = D_;

    const int wg = blockIdx.y * 8 + blockIdx.x;
    const int bm = (wg % 8) * 256;
    const int bn = (wg / 8) * 256;

    const short* A16 = qhp + (long)bz * L_ * D_;
    const short* Bt  = khp + (long)bz * L_ * D_;
    short* C = Cp + (long)bz * ((long)L_ * L_);

    const int wr = wid >> 2, wc = wid & 3;
    const int lr = lane & 15, lk = lane >> 4;

    f32x4 acc[8][4];
#pragma unroll
    for (int m = 0; m < 8; ++m)
#pragma unroll
        for (int n = 0; n < 4; ++n) acc[m][n] = (f32x4)0.f;

    pipeline_loop8(A16, Bt, smem, smem + 32768, bm, bn, K, t, wid, wr, wc, lr, lk, acc);

    const bool msk = (mflag[0] != 0);
    epilogue_f16_bounce8<1>(smem + wid * 4096, C, L_,
                            bm + wr * 128, bn + wc * 64, lr, lk, lane,
                            acc, 0.125f, msk);
}

// ============== 4-wave 128x128 quad-buffered pipeline (geometry fixed) ==============
// 256 thr, LDS 64KB total: A 4 x 4096 shorts (8KB) | B same. 2 blocks/CU.
// Per thread per tile: 4 gload_lds -> vmcnt gates 8/4/0, depth 3 (as loop8).

__device__ __forceinline__ void stage4(
    const short* __restrict__ A16, const short* __restrict__ Bt,
    short* __restrict__ As, short* __restrict__ Bs,
    int bm, int bn, int k0, int K, int t, int wid)
{
    const int r0 = t >> 2;    // 0..63 row within 64-row chunk (r0 = wid*16 + lane>>2)
    const int sl = t & 3;     // 16B slot
#pragma unroll
    for (int i = 0; i < 2; ++i) {
        const int r = i * 64 + r0;
        const short* g = A16 + (long)(bm + r) * K + k0 + ((sl ^ ((r >> 1) & 3)) << 3);
        gload_lds16(g, As + i * 2048 + wid * 512);   // wave covers 16 rows = 512 shorts
    }
#pragma unroll
    for (int i = 0; i < 2; ++i) {
        const int r = i * 64 + r0;
        const short* g = Bt + (long)(bn + r) * K + k0 + ((sl ^ ((r >> 1) & 3)) << 3);
        gload_lds16(g, Bs + i * 2048 + wid * 512);
    }
}

__device__ __forceinline__ void compute32_w4(
    const short* __restrict__ As, const short* __restrict__ Bs,
    int wr, int wc, int lr, int lk, f32x4 (&acc)[4][4])
{
    f16x8 a[4], b[4];
#pragma unroll
    for (int m = 0; m < 4; ++m) {
        const int r = wr * 64 + m * 16 + lr;
        a[m] = *(const f16x8*)&As[r * 32 + ((lk ^ ((r >> 1) & 3)) << 3)];
    }
#pragma unroll
    for (int n = 0; n < 4; ++n) {
        const int c = wc * 64 + n * 16 + lr;
        b[n] = *(const f16x8*)&Bs[c * 32 + ((lk ^ ((c >> 1) & 3)) << 3)];
    }
    __builtin_amdgcn_s_setprio(1);
#pragma unroll
    for (int m = 0; m < 4; ++m)
#pragma unroll
        for (int n = 0; n < 4; ++n)
            acc[m][n] = __builtin_amdgcn_mfma_f32_16x16x32_f16(a[m], b[n], acc[m][n], 0, 0, 0);
    __builtin_amdgcn_s_setprio(0);
}

// wave 64x64 f16 LDS-bounce epilogue (4096-short wave region)
__device__ __forceinline__ void epilogue_f16_bounce4(
    short* __restrict__ lw, short* __restrict__ C, long N,
    int rowBase, int colBase, int lr, int lk, int lane,
    const f32x4 (&acc)[4][4])
{
#pragma unroll
    for (int m = 0; m < 4; ++m) {
        const int rl0 = m * 16 + lk * 4;
#pragma unroll
        for (int n = 0; n < 4; ++n) {
            const int cl = n * 16 + lr;
            const int slot = cl >> 3, cw = cl & 7;
#pragma unroll
            for (int g = 0; g < 4; ++g) {
                const int rl = rl0 + g;
                lw[rl * 64 + ((slot ^ (rl & 7)) << 3) + cw] = f2h_bits(acc[m][n][g]);
            }
        }
    }
    const int l8 = lane & 7, lr8 = lane >> 3;
#pragma unroll
    for (int it = 0; it < 8; ++it) {
        const int rl = it * 8 + lr8;
        const int cl = (l8 ^ (rl & 7)) << 3;
        s16x8 d = *(const s16x8*)&lw[rl * 64 + (l8 << 3)];
        *(s16x8*)&C[(long)(rowBase + rl) * N + colBase + cl] = d;
    }
}

__device__ __forceinline__ void pipeline_loop4(
    const short* __restrict__ A16, const short* __restrict__ Bt,
    short* __restrict__ Abuf, short* __restrict__ Bbuf,
    int bm, int bn, int K, int t, int wid,
    int wr, int wc, int lr, int lk, f32x4 (&acc)[4][4])
{
    stage4(A16, Bt, Abuf + 0 * 4096, Bbuf + 0 * 4096, bm, bn, 0,  K, t, wid);
    stage4(A16, Bt, Abuf + 1 * 4096, Bbuf + 1 * 4096, bm, bn, 32, K, t, wid);
    stage4(A16, Bt, Abuf + 2 * 4096, Bbuf + 2 * 4096, bm, bn, 64, K, t, wid);

    const int nt = K / 32;
    for (int ti = 0; ti < nt; ++ti) {
        if (ti + 2 < nt)      asm volatile("s_waitcnt vmcnt(8)" ::: "memory");
        else if (ti + 1 < nt) asm volatile("s_waitcnt vmcnt(4)" ::: "memory");
        else                  asm volatile("s_waitcnt vmcnt(0)" ::: "memory");
        __builtin_amdgcn_sched_barrier(0);
        __builtin_amdgcn_s_barrier();
        __builtin_amdgcn_sched_barrier(0);
        asm volatile("" ::: "memory");
        if (ti + 3 < nt) {
            const int nb = (ti + 3) & 3;
            stage4(A16, Bt, Abuf + nb * 4096, Bbuf + nb * 4096, bm, bn,
                   (ti + 3) * 32, K, t, wid);
        }
        const int cb = ti & 3;
        compute32_w4(Abuf + cb * 4096, Bbuf + cb * 4096, wr, wc, lr, lk, acc);
    }
    __syncthreads();
}

// generic pipelined GEMM. OMODE: 0 = f16 [M,N]; 2 = f32 [M,N].
template<int OMODE>
__global__ __launch_bounds__(256) void hgemm4_pipe(
    const short* __restrict__ A16p, const short* __restrict__ Btp, void* __restrict__ Cp_,
    int N, int K, long sA, long sB, long sC)
{
    __shared__ short smem[16384 + 16384];   // 64 KB

    const int t    = threadIdx.x;
    const int wid  = t >> 6;
    const int lane = t & 63;
    const int bz   = blockIdx.z;

    const int gx = gridDim.x, gy = gridDim.y;
    const int wg = blockIdx.y * gx + blockIdx.x;
    const int bm = (wg % gy) * 128;   // M-panel pinned to one XCD (gy%8==0)
    const int bn = (wg / gy) * 128;

    const short* A16 = A16p + (long)bz * sA;
    const short* Bt  = Btp + (long)bz * sB;

    const int wr = wid >> 1, wc = wid & 1;
    const int lr = lane & 15, lk = lane >> 4;

    f32x4 acc[4][4];
#pragma unroll
    for (int m = 0; m < 4; ++m)
#pragma unroll
        for (int n = 0; n < 4; ++n) acc[m][n] = (f32x4)0.f;

    pipeline_loop4(A16, Bt, smem, smem + 16384, bm, bn, K, t, wid, wr, wc, lr, lk, acc);

    if constexpr (OMODE == 2) {
        float* C = (float*)Cp_ + (long)bz * sC;
#pragma unroll
        for (int m = 0; m < 4; ++m) {
            const int r0 = bm + wr * 64 + m * 16 + lk * 4;
#pragma unroll
            for (int n = 0; n < 4; ++n) {
                const int c = bn + wc * 64 + n * 16 + lr;
#pragma unroll
                for (int g = 0; g < 4; ++g)
                    C[(long)(r0 + g) * N + c] = acc[m][n][g];
            }
        }
    } else {
        short* C = (short*)Cp_ + (long)bz * sC;
        epilogue_f16_bounce4(smem + wid * 4096, C, N,
                             bm + wr * 64, bn + wc * 64, lr, lk, lane, acc);
    }
}

// fused QKV projections, pipelined. grid (8, 64, 3), 256 threads.
__global__ __launch_bounds__(256) void hgemm4_proj(
    const short* __restrict__ qf, const short* __restrict__ kf, const short* __restrict__ vf,
    const short* __restrict__ wq, const short* __restrict__ wk, const short* __restrict__ wv,
    short* __restrict__ qh, short* __restrict__ kh, short* __restrict__ vT)
{
    __shared__ short smem[16384 + 16384];   // 64 KB

    const int t    = threadIdx.x;
    const int wid  = t >> 6;
    const int lane = t & 63;
    const int bz   = blockIdx.z;
    const int K    = D_;
    const int N    = D_;

    const short* A16 = (bz == 0) ? qf : (bz == 1) ? kf : vf;
    const short* Bt  = (bz == 0) ? wq : (bz == 1) ? wk : wv;

    const int gx = gridDim.x, gy = gridDim.y;
    const int wg = blockIdx.y * gx + blockIdx.x;
    const int bm = (wg % gy) * 128;
    const int bn = (wg / gy) * 128;

    const int wr = wid >> 1, wc = wid & 1;
    const int lr = lane & 15, lk = lane >> 4;

    f32x4 acc[4][4];
#pragma unroll
    for (int m = 0; m < 4; ++m)
#pragma unroll
        for (int n = 0; n < 4; ++n) acc[m][n] = (f32x4)0.f;

    pipeline_loop4(A16, Bt, smem, smem + 16384, bm, bn, K, t, wid, wr, wc, lr, lk, acc);

    if (bz < 2) {
        short* C = (bz == 0) ? qh : kh;
        epilogue_f16_bounce4(smem + wid * 4096, C, N,
                             bm + wr * 64, bn + wc * 64, lr, lk, lane, acc);
    } else {
#pragma unroll
        for (int m = 0; m < 4; ++m) {
            const int rg = bm + wr * 64 + m * 16 + lk * 4;
            const long rb = (long)(rg >> 11) * ((long)N * L_) + (rg & (L_ - 1));
#pragma unroll
            for (int n = 0; n < 4; ++n) {
                const int c = bn + wc * 64 + n * 16 + lr;
                u16x4 v;
#pragma unroll
                for (int g = 0; g < 4; ++g) v[g] = (unsigned short)f2h_bits(acc[m][n][g]);
                *(u16x4*)&vT[rb + (long)c * L_] = v;
            }
        }
    }
}

// ================= small kernels (proven) =================

__global__ __launch_bounds__(256) void cvt_w4_k(
    const float* __restrict__ W_Q, const float* __restrict__ W_K,
    const float* __restrict__ W_V, const float* __restrict__ W_O,
    short* __restrict__ dst)
{
    const int w = blockIdx.y;
    const float* src = (w == 0) ? W_Q : (w == 1) ? W_K : (w == 2) ? W_V : W_O;
    short* out = dst + (size_t)w * D_ * D_;
    const int i = blockIdx.x * 256 + threadIdx.x;
    float4 a = ((const float4*)src)[2 * i];
    float4 b = ((const float4*)src)[2 * i + 1];
    *(s16x8*)&out[i * 8] = cvt8h(a, b);
}

__global__ __launch_bounds__(256) void cvt_qkv_k(
    const float* __restrict__ Q, const float* __restrict__ K,
    const float* __restrict__ V, short* __restrict__ dst)
{
    const int w = blockIdx.y;
    const float* src = (w == 0) ? Q : (w == 1) ? K : V;
    short* out = dst + (size_t)w * B_ * L_ * D_;
    const int i = blockIdx.x * 256 + threadIdx.x;
    float4 a = ((const float4*)src)[2 * i];
    float4 b = ((const float4*)src)[2 * i + 1];
    *(s16x8*)&out[i * 8] = cvt8h(a, b);
}

// row softmax over f16 unnormalized scores (rows of 2048):
// writes fp32 normalized attn (d_out) + f16 normalized copy in place.
__global__ __launch_bounds__(256) void softmax_rows_k(
    short* __restrict__ S16, float* __restrict__ Sout)
{
    const long row = blockIdx.x;
    short* p16 = S16 + row * (long)L_;
    float* pf  = Sout + row * (long)L_;
    const int tid = threadIdx.x;

    union { s16x8 v; _Float16 h[8]; } u;
    u.v = ((const s16x8*)p16)[tid];
    float f[8];
#pragma unroll
    for (int j = 0; j < 8; ++j) f[j] = (float)u.h[j];

    float m = f[0];
#pragma unroll
    for (int j = 1; j < 8; ++j) m = fmaxf(m, f[j]);
#pragma unroll
    for (int o = 32; o > 0; o >>= 1) m = fmaxf(m, __shfl_xor(m, o, 64));

    __shared__ float wmax[4], wsum[4];
    if ((tid & 63) == 0) wmax[tid >> 6] = m;
    __syncthreads();
    m = fmaxf(fmaxf(wmax[0], wmax[1]), fmaxf(wmax[2], wmax[3]));

    float s = 0.f;
#pragma unroll
    for (int j = 0; j < 8; ++j) { f[j] = expf(f[j] - m); s += f[j]; }
#pragma unroll
    for (int o = 32; o > 0; o >>= 1) s += __shfl_xor(s, o, 64);
    if ((tid & 63) == 0) wsum[tid >> 6] = s;
    __syncthreads();
    s = wsum[0] + wsum[1] + wsum[2] + wsum[3];

    const float inv = 1.f / s;
#pragma unroll
    for (int j = 0; j < 8; ++j) f[j] = f[j] * inv;

    float4 a, b;
    a.x = f[0]; a.y = f[1]; a.z = f[2]; a.w = f[3];
    b.x = f[4]; b.y = f[5]; b.z = f[6]; b.w = f[7];
    ((float4*)pf)[2 * tid]     = a;
    ((float4*)pf)[2 * tid + 1] = b;
    ((s16x8*)p16)[tid] = cvt8h(a, b);
}

extern "C" void kernel_launch(void* const* d_in, const int* in_sizes, int n_in,
                              void* d_out, int out_size, void* d_ws, size_t ws_size,
                              hipStream_t stream) {
    const float* Q   = (const float*)d_in[0];
    const float* K   = (const float*)d_in[1];
    const float* V   = (const float*)d_in[2];
    const float* W_Q = (const float*)d_in[3];
    const float* W_K = (const float*)d_in[4];
    const float* W_V = (const float*)d_in[5];
    const float* W_O = (const float*)d_in[6];
    const int* masked = (const int*)d_in[7];

    float* out  = (float*)d_out;                    // [4,2048,1024]
    float* attn = out + (size_t)B_ * L_ * D_;       // [4,2048,2048]

    // ws layout (shorts): 8MB weights | qh 16.8 | kh 16.8 | vT 16.8 | attn16 33.6
    short* wq = (short*)d_ws;
    short* wk = wq + (size_t)D_ * D_;
    short* wv = wk + (size_t)D_ * D_;
    short* wo = wv + (size_t)D_ * D_;
    short* qh = wo + (size_t)D_ * D_;               // [8192,1024] f16
    short* kh = qh + (size_t)B_ * L_ * D_;
    short* vT = kh + (size_t)B_ * L_ * D_;          // [4][1024][2048] f16
    short* attn16 = vT + (size_t)B_ * L_ * D_;      // [4][2048][2048] f16
    short* xh = qh;                                 // reuse after scores

    // fp16 Q/K/V copies live in d_out's attn region (dead before softmax writes it)
    short* qf = (short*)attn;                       // 3 x 16.8 MB <= 67 MB
    short* kf = qf + (size_t)B_ * L_ * D_;
    short* vf = kf + (size_t)B_ * L_ * D_;

    const long SLD = (long)L_ * D_;
    const long SLL = (long)L_ * L_;

    // 1) weights + inputs fp32 -> fp16
    cvt_w4_k<<<dim3(D_ * D_ / 8 / 256, 4), 256, 0, stream>>>(W_Q, W_K, W_V, W_O, wq);
    cvt_qkv_k<<<dim3(B_ * L_ * D_ / 8 / 256, 3), 256, 0, stream>>>(Q, K, V, qf);

    // 2) fused QKV projections: pipelined 128^2, 1536 blocks = 3 full rounds at 2/CU
    hgemm4_proj<<<dim3(8, 64, 3), 256, 0, stream>>>(
        qf, kf, vf, wq, wk, wv, qh, kh, vT);

    // 3) scores = q @ k^T / 8 -> f16 UNNORMALIZED into attn16 (+ faithful mask)
    hgemm8_scores<<<dim3(8, 8, B_), 512, 0, stream>>>(qh, kh, attn16, masked);

    // 4) softmax rows: read f16 scores, write fp32 attn + normalized f16 in place
    softmax_rows_k<<<dim3(B_ * L_), 256, 0, stream>>>(attn16, attn);

    // 5) x = attn16 @ vT -> f16 x : pipelined, 512 blocks = 1 full round at 2/CU
    hgemm4_pipe<0><<<dim3(8, 16, B_), 256, 0, stream>>>(
        attn16, vT, xh, D_, L_, SLL, SLD, SLD);

    // 6) out = x @ W_O^T -> fp32 : pipelined, 512 blocks
    hgemm4_pipe<2><<<dim3(8, 64, 1), 256, 0, stream>>>(
        xh, wo, out, D_, D_, 0, 0, 0);
}

// Round 18
// 219.001 us; speedup vs baseline: 1.1033x; 1.0816x over previous
//
#include <hip/hip_runtime.h>
#include <math.h>

// MaskedMultiHeadAttention (B=4, L=2048, D=1024), fp32 in/out, fp16-MFMA internals.
// d_out = [ out : 4*2048*1024 f32 | attn : 4*2048*2048 f32 ]
// ws (92MB): wq wk wv wo (f16) | qh | kh | vT | attn16 (f16); x reuses qh.
// Round 16: proj/PV/out-proj -> BK=64 double-buffered 2-phase counted pipeline
// (T3-minimum: stage(t+1) issued after barrier, vmcnt(0) waits land one full
// compute-phase after issue). Classic BKK=64 staging/compute geometry reused
// verbatim; 64KB LDS -> 2 blocks/CU; all grids full scheduling rounds.
// Scores stays on the proven 8-wave 256x256 quad pipeline.

static constexpr int B_ = 4;
static constexpr int L_ = 2048;
static constexpr int D_ = 1024;

typedef _Float16 f16x8 __attribute__((ext_vector_type(8)));
typedef float    f32x4 __attribute__((ext_vector_type(4)));
typedef short    s16x8 __attribute__((ext_vector_type(8)));
typedef unsigned short u16x4 __attribute__((ext_vector_type(4)));

typedef __attribute__((address_space(1))) const unsigned int GU32;
typedef __attribute__((address_space(3))) unsigned int LU32;

__device__ __forceinline__ void gload_lds16(const void* g, void* l) {
    __builtin_amdgcn_global_load_lds((GU32*)g, (LU32*)l, 16, 0, 0);
}

__device__ __forceinline__ short f2h_bits(float x) {
    union { _Float16 h; short s; } u;
    u.h = (_Float16)x;
    return u.s;
}

__device__ __forceinline__ s16x8 cvt8h(float4 a, float4 b) {
    union { _Float16 h[8]; s16x8 s; } u;
    u.h[0] = (_Float16)a.x; u.h[1] = (_Float16)a.y;
    u.h[2] = (_Float16)a.z; u.h[3] = (_Float16)a.w;
    u.h[4] = (_Float16)b.x; u.h[5] = (_Float16)b.y;
    u.h[6] = (_Float16)b.z; u.h[7] = (_Float16)b.w;
    return u.s;
}

// ================= shared classic-geometry pieces =================

// One BK=64 step: 2 k-subtiles x (8 ds_read_b128 + 16 MFMA) per wave.
__device__ __forceinline__ void compute_step(
    const short* __restrict__ As, const short* __restrict__ Bs,
    int wr, int wc, int lr, int lk, f32x4 (&acc)[4][4])
{
#pragma unroll
    for (int kk = 0; kk < 2; ++kk) {
        const int slotk = kk * 4 + lk;
        f16x8 a[4], b[4];
#pragma unroll
        for (int m = 0; m < 4; ++m) {
            const int r = wr * 64 + m * 16 + lr;
            a[m] = *(const f16x8*)&As[r * 64 + ((slotk ^ (r & 7)) << 3)];
        }
#pragma unroll
        for (int n = 0; n < 4; ++n) {
            const int c = wc * 64 + n * 16 + lr;
            b[n] = *(const f16x8*)&Bs[c * 64 + ((slotk ^ (c & 7)) << 3)];
        }
        __builtin_amdgcn_s_setprio(1);
#pragma unroll
        for (int m = 0; m < 4; ++m)
#pragma unroll
            for (int n = 0; n < 4; ++n)
                acc[m][n] = __builtin_amdgcn_mfma_f32_16x16x32_f16(a[m], b[n], acc[m][n], 0, 0, 0);
        __builtin_amdgcn_s_setprio(0);
    }
}

// Classic BKK=64 staging of one 128x64 tile pair into a given buffer.
__device__ __forceinline__ void stage64(
    const short* __restrict__ A16, const short* __restrict__ Bt,
    short* __restrict__ As, short* __restrict__ Bs,
    int bm, int bn, int k0, int K, int srow, int sslot, int wid)
{
#pragma unroll
    for (int i = 0; i < 4; ++i) {
        const int rb = i * 32 + srow;
        const short* g = Bt + (long)(bn + rb) * K + k0 + ((sslot ^ (rb & 7)) << 3);
        gload_lds16(g, &Bs[i * 2048 + wid * 512]);
    }
#pragma unroll
    for (int i = 0; i < 4; ++i) {
        const int ra = i * 32 + srow;
        const short* g = A16 + (long)(bm + ra) * K + k0 + ((sslot ^ (ra & 7)) << 3);
        gload_lds16(g, &As[i * 2048 + wid * 512]);
    }
}

// wave 64x64 f16 LDS-bounce epilogue (4096-short wave region)
template<int APPLY_SM>
__device__ __forceinline__ void epilogue_f16_bounce(
    short* __restrict__ lw, short* __restrict__ C, long N,
    int bm, int bn, int wr, int wc, int lr, int lk, int lane,
    const f32x4 (&acc)[4][4], float scale, bool msk)
{
#pragma unroll
    for (int m = 0; m < 4; ++m) {
        const int rl0 = m * 16 + lk * 4;
#pragma unroll
        for (int n = 0; n < 4; ++n) {
            const int cl = n * 16 + lr;
            const int slot = cl >> 3, cw = cl & 7;
#pragma unroll
            for (int g = 0; g < 4; ++g) {
                const int rl = rl0 + g;
                float v = acc[m][n][g];
                if constexpr (APPLY_SM) {
                    v *= scale;
                    if (msk && (bn + wc * 64 + cl) <= (bm + wr * 64 + rl)) v = -INFINITY;
                }
                lw[rl * 64 + ((slot ^ (rl & 7)) << 3) + cw] = f2h_bits(v);
            }
        }
    }
    const int l8 = lane & 7, lr8 = lane >> 3;
#pragma unroll
    for (int it = 0; it < 8; ++it) {
        const int rl = it * 8 + lr8;
        const int cl = (l8 ^ (rl & 7)) << 3;
        s16x8 d = *(const s16x8*)&lw[rl * 64 + (l8 << 3)];
        *(s16x8*)&C[(long)(bm + wr * 64 + rl) * N + bn + wc * 64 + cl] = d;
    }
}

// 2-phase double-buffered BK=64 K-loop: gate vmcnt(0) lands one full compute
// phase after the loads were issued; stage(t+1) issued after the barrier.
__device__ __forceinline__ void pipeline2_64(
    const short* __restrict__ A16, const short* __restrict__ Bt,
    short* __restrict__ smem,
    int bm, int bn, int K, int srow, int sslot, int wid,
    int wr, int wc, int lr, int lk, f32x4 (&acc)[4][4])
{
    // buffer b: smem + b*16384 shorts; layout A[8192] | B[8192] (32KB each)
    stage64(A16, Bt, smem, smem + 8192, bm, bn, 0, K, srow, sslot, wid);

    const int nt = K / 64;
    for (int ti = 0; ti < nt; ++ti) {
        asm volatile("s_waitcnt vmcnt(0)" ::: "memory");
        __builtin_amdgcn_sched_barrier(0);
        __builtin_amdgcn_s_barrier();
        __builtin_amdgcn_sched_barrier(0);
        const int cur = (ti & 1) * 16384;
        if (ti + 1 < nt) {
            const int nxt = ((ti + 1) & 1) * 16384;
            stage64(A16, Bt, smem + nxt, smem + nxt + 8192, bm, bn,
                    (ti + 1) * 64, K, srow, sslot, wid);
        }
        compute_step(smem + cur, smem + cur + 8192, wr, wc, lr, lk, acc);
    }
    __syncthreads();   // all buffer reads done before LDS reuse by epilogue
}

// generic pipelined GEMM, 128x128 tile. OMODE: 0 = f16 [M,N]; 2 = f32 [M,N].
template<int OMODE>
__global__ __launch_bounds__(256) void hgemm64_pipe(
    const short* __restrict__ A16p, const short* __restrict__ Btp, void* __restrict__ Cp_,
    int N, int K, long sA, long sB, long sC)
{
    __shared__ short smem[32768];   // 64 KB

    const int t    = threadIdx.x;
    const int wid  = t >> 6;
    const int lane = t & 63;
    const int bz   = blockIdx.z;

    const int gx = gridDim.x, gy = gridDim.y;
    const int wg = blockIdx.y * gx + blockIdx.x;
    const int bm = (wg % gy) * 128;   // M-panel pinned to one XCD (gy%8==0)
    const int bn = (wg / gy) * 128;

    const short* A16 = A16p + (long)bz * sA;
    const short* Bt  = Btp + (long)bz * sB;

    const int wr = wid >> 1, wc = wid & 1;
    const int lr = lane & 15, lk = lane >> 4;
    const int srow = t >> 3, sslot = t & 7;

    f32x4 acc[4][4];
#pragma unroll
    for (int m = 0; m < 4; ++m)
#pragma unroll
        for (int n = 0; n < 4; ++n) acc[m][n] = (f32x4)0.f;

    pipeline2_64(A16, Bt, smem, bm, bn, K, srow, sslot, wid, wr, wc, lr, lk, acc);

    if constexpr (OMODE == 2) {
        float* C = (float*)Cp_ + (long)bz * sC;
#pragma unroll
        for (int m = 0; m < 4; ++m) {
            const int r0 = bm + wr * 64 + m * 16 + lk * 4;
#pragma unroll
            for (int n = 0; n < 4; ++n) {
                const int c = bn + wc * 64 + n * 16 + lr;
#pragma unroll
                for (int g = 0; g < 4; ++g)
                    C[(long)(r0 + g) * N + c] = acc[m][n][g];
            }
        }
    } else {
        short* C = (short*)Cp_ + (long)bz * sC;
        epilogue_f16_bounce<0>(smem + wid * 4096, C, N, bm, bn, wr, wc, lr, lk, lane,
                               acc, 1.f, false);
    }
}

// fused QKV projections, 2-phase pipeline. grid (8, 64, 3), 256 threads.
__global__ __launch_bounds__(256) void hgemm64_proj(
    const short* __restrict__ qf, const short* __restrict__ kf, const short* __restrict__ vf,
    const short* __restrict__ wq, const short* __restrict__ wk, const short* __restrict__ wv,
    short* __restrict__ qh, short* __restrict__ kh, short* __restrict__ vT)
{
    __shared__ short smem[32768];   // 64 KB

    const int t    = threadIdx.x;
    const int wid  = t >> 6;
    const int lane = t & 63;
    const int bz   = blockIdx.z;
    const int K    = D_;
    const int N    = D_;

    const short* A16 = (bz == 0) ? qf : (bz == 1) ? kf : vf;
    const short* Bt  = (bz == 0) ? wq : (bz == 1) ? wk : wv;

    const int gx = gridDim.x, gy = gridDim.y;
    const int wg = blockIdx.y * gx + blockIdx.x;
    const int bm = (wg % gy) * 128;
    const int bn = (wg / gy) * 128;

    const int wr = wid >> 1, wc = wid & 1;
    const int lr = lane & 15, lk = lane >> 4;
    const int srow = t >> 3, sslot = t & 7;

    f32x4 acc[4][4];
#pragma unroll
    for (int m = 0; m < 4; ++m)
#pragma unroll
        for (int n = 0; n < 4; ++n) acc[m][n] = (f32x4)0.f;

    pipeline2_64(A16, Bt, smem, bm, bn, K, srow, sslot, wid, wr, wc, lr, lk, acc);

    if (bz < 2) {
        short* C = (bz == 0) ? qh : kh;
        epilogue_f16_bounce<0>(smem + wid * 4096, C, N, bm, bn, wr, wc, lr, lk, lane,
                               acc, 1.f, false);
    } else {
#pragma unroll
        for (int m = 0; m < 4; ++m) {
            const int rg = bm + wr * 64 + m * 16 + lk * 4;
            const long rb = (long)(rg >> 11) * ((long)N * L_) + (rg & (L_ - 1));
#pragma unroll
            for (int n = 0; n < 4; ++n) {
                const int c = bn + wc * 64 + n * 16 + lr;
                u16x4 v;
#pragma unroll
                for (int g = 0; g < 4; ++g) v[g] = (unsigned short)f2h_bits(acc[m][n][g]);
                *(u16x4*)&vT[rb + (long)c * L_] = v;
            }
        }
    }
}

// ============== 8-wave 256x256 quad pipeline (round-12 proven, scores) ==============

__device__ __forceinline__ void stage8(
    const short* __restrict__ A16, const short* __restrict__ Bt,
    short* __restrict__ As, short* __restrict__ Bs,
    int bm, int bn, int k0, int K, int t, int wid)
{
    const int r0 = t >> 2;
    const int sl = t & 3;
#pragma unroll
    for (int i = 0; i < 2; ++i) {
        const int r = i * 128 + r0;
        const short* g = A16 + (long)(bm + r) * K + k0 + ((sl ^ ((r >> 1) & 3)) << 3);
        gload_lds16(g, As + i * 4096 + wid * 512);
    }
#pragma unroll
    for (int i = 0; i < 2; ++i) {
        const int r = i * 128 + r0;
        const short* g = Bt + (long)(bn + r) * K + k0 + ((sl ^ ((r >> 1) & 3)) << 3);
        gload_lds16(g, Bs + i * 4096 + wid * 512);
    }
}

__device__ __forceinline__ void compute32_w8(
    const short* __restrict__ As, const short* __restrict__ Bs,
    int wr, int wc, int lr, int lk, f32x4 (&acc)[8][4])
{
    f16x8 a[8], b[4];
#pragma unroll
    for (int m = 0; m < 8; ++m) {
        const int r = wr * 128 + m * 16 + lr;
        a[m] = *(const f16x8*)&As[r * 32 + ((lk ^ ((r >> 1) & 3)) << 3)];
    }
#pragma unroll
    for (int n = 0; n < 4; ++n) {
        const int c = wc * 64 + n * 16 + lr;
        b[n] = *(const f16x8*)&Bs[c * 32 + ((lk ^ ((c >> 1) & 3)) << 3)];
    }
    __builtin_amdgcn_s_setprio(1);
#pragma unroll
    for (int m = 0; m < 8; ++m)
#pragma unroll
        for (int n = 0; n < 4; ++n)
            acc[m][n] = __builtin_amdgcn_mfma_f32_16x16x32_f16(a[m], b[n], acc[m][n], 0, 0, 0);
    __builtin_amdgcn_s_setprio(0);
}

template<int APPLY_SM>
__device__ __forceinline__ void epilogue_f16_bounce8(
    short* __restrict__ lw, short* __restrict__ C, long N,
    int rowBase, int colBase, int lr, int lk, int lane,
    const f32x4 (&acc)[8][4], float scale, bool msk)
{
#pragma unroll
    for (int h = 0; h < 2; ++h) {
#pragma unroll
        for (int mm = 0; mm < 4; ++mm) {
            const int m = h * 4 + mm;
            const int rl0 = mm * 16 + lk * 4;
#pragma unroll
            for (int n = 0; n < 4; ++n) {
                const int cl = n * 16 + lr;
                const int slot = cl >> 3, cw = cl & 7;
#pragma unroll
                for (int g = 0; g < 4; ++g) {
                    const int rl = rl0 + g;
                    float v = acc[m][n][g];
                    if constexpr (APPLY_SM) {
                        v *= scale;
                        if (msk && (colBase + cl) <= (rowBase + h * 64 + rl)) v = -INFINITY;
                    }
                    lw[rl * 64 + ((slot ^ (rl & 7)) << 3) + cw] = f2h_bits(v);
                }
            }
        }
        const int l8 = lane & 7, lr8 = lane >> 3;
#pragma unroll
        for (int it = 0; it < 8; ++it) {
            const int rl = it * 8 + lr8;
            const int cl = (l8 ^ (rl & 7)) << 3;
            s16x8 d = *(const s16x8*)&lw[rl * 64 + (l8 << 3)];
            *(s16x8*)&C[(long)(rowBase + h * 64 + rl) * N + colBase + cl] = d;
        }
    }
}

__device__ __forceinline__ void pipeline_loop8(
    const short* __restrict__ A16, const short* __restrict__ Bt,
    short* __restrict__ Abuf, short* __restrict__ Bbuf,
    int bm, int bn, int K, int t, int wid,
    int wr, int wc, int lr, int lk, f32x4 (&acc)[8][4])
{
    stage8(A16, Bt, Abuf + 0 * 8192, Bbuf + 0 * 8192, bm, bn, 0,  K, t, wid);
    stage8(A16, Bt, Abuf + 1 * 8192, Bbuf + 1 * 8192, bm, bn, 32, K, t, wid);
    stage8(A16, Bt, Abuf + 2 * 8192, Bbuf + 2 * 8192, bm, bn, 64, K, t, wid);

    const int nt = K / 32;
    for (int ti = 0; ti < nt; ++ti) {
        if (ti + 2 < nt)      asm volatile("s_waitcnt vmcnt(8)" ::: "memory");
        else if (ti + 1 < nt) asm volatile("s_waitcnt vmcnt(4)" ::: "memory");
        else                  asm volatile("s_waitcnt vmcnt(0)" ::: "memory");
        __builtin_amdgcn_sched_barrier(0);
        __builtin_amdgcn_s_barrier();
        __builtin_amdgcn_sched_barrier(0);
        asm volatile("" ::: "memory");
        if (ti + 3 < nt) {
            const int nb = (ti + 3) & 3;
            stage8(A16, Bt, Abuf + nb * 8192, Bbuf + nb * 8192, bm, bn,
                   (ti + 3) * 32, K, t, wid);
        }
        const int cb = ti & 3;
        compute32_w8(Abuf + cb * 8192, Bbuf + cb * 8192, wr, wc, lr, lk, acc);
    }
    __syncthreads();
}

// scores = qh @ kh^T * 0.125 -> f16 attn16 (+ faithful-buggy tril mask)
__global__ __launch_bounds__(512) void hgemm8_scores(
    const short* __restrict__ qhp, const short* __restrict__ khp,
    short* __restrict__ Cp, const int* __restrict__ mflag)
{
    __shared__ short smem[65536];

    const int t    = threadIdx.x;
    const int wid  = t >> 6;
    const int lane = t & 63;
    const int bz   = blockIdx.z;
    const int K    = D_;

    const int wg = blockIdx.y * 8 + blockIdx.x;
    const int bm = (wg % 8) * 256;
    const int bn = (wg / 8) * 256;

    const short* A16 = qhp + (long)bz * L_ * D_;
    const short* Bt  = khp + (long)bz * L_ * D_;
    short* C = Cp + (long)bz * ((long)L_ * L_);

    const int wr = wid >> 2, wc = wid & 3;
    const int lr = lane & 15, lk = lane >> 4;

    f32x4 acc[8][4];
#pragma unroll
    for (int m = 0; m < 8; ++m)
#pragma unroll
        for (int n = 0; n < 4; ++n) acc[m][n] = (f32x4)0.f;

    pipeline_loop8(A16, Bt, smem, smem + 32768, bm, bn, K, t, wid, wr, wc, lr, lk, acc);

    const bool msk = (mflag[0] != 0);
    epilogue_f16_bounce8<1>(smem + wid * 4096, C, L_,
                            bm + wr * 128, bn + wc * 64, lr, lk, lane,
                            acc, 0.125f, msk);
}

// ================= small kernels (proven) =================

__global__ __launch_bounds__(256) void cvt_w4_k(
    const float* __restrict__ W_Q, const float* __restrict__ W_K,
    const float* __restrict__ W_V, const float* __restrict__ W_O,
    short* __restrict__ dst)
{
    const int w = blockIdx.y;
    const float* src = (w == 0) ? W_Q : (w == 1) ? W_K : (w == 2) ? W_V : W_O;
    short* out = dst + (size_t)w * D_ * D_;
    const int i = blockIdx.x * 256 + threadIdx.x;
    float4 a = ((const float4*)src)[2 * i];
    float4 b = ((const float4*)src)[2 * i + 1];
    *(s16x8*)&out[i * 8] = cvt8h(a, b);
}

__global__ __launch_bounds__(256) void cvt_qkv_k(
    const float* __restrict__ Q, const float* __restrict__ K,
    const float* __restrict__ V, short* __restrict__ dst)
{
    const int w = blockIdx.y;
    const float* src = (w == 0) ? Q : (w == 1) ? K : V;
    short* out = dst + (size_t)w * B_ * L_ * D_;
    const int i = blockIdx.x * 256 + threadIdx.x;
    float4 a = ((const float4*)src)[2 * i];
    float4 b = ((const float4*)src)[2 * i + 1];
    *(s16x8*)&out[i * 8] = cvt8h(a, b);
}

// row softmax over f16 unnormalized scores (rows of 2048):
// writes fp32 normalized attn (d_out) + f16 normalized copy in place.
__global__ __launch_bounds__(256) void softmax_rows_k(
    short* __restrict__ S16, float* __restrict__ Sout)
{
    const long row = blockIdx.x;
    short* p16 = S16 + row * (long)L_;
    float* pf  = Sout + row * (long)L_;
    const int tid = threadIdx.x;

    union { s16x8 v; _Float16 h[8]; } u;
    u.v = ((const s16x8*)p16)[tid];
    float f[8];
#pragma unroll
    for (int j = 0; j < 8; ++j) f[j] = (float)u.h[j];

    float m = f[0];
#pragma unroll
    for (int j = 1; j < 8; ++j) m = fmaxf(m, f[j]);
#pragma unroll
    for (int o = 32; o > 0; o >>= 1) m = fmaxf(m, __shfl_xor(m, o, 64));

    __shared__ float wmax[4], wsum[4];
    if ((tid & 63) == 0) wmax[tid >> 6] = m;
    __syncthreads();
    m = fmaxf(fmaxf(wmax[0], wmax[1]), fmaxf(wmax[2], wmax[3]));

    float s = 0.f;
#pragma unroll
    for (int j = 0; j < 8; ++j) { f[j] = expf(f[j] - m); s += f[j]; }
#pragma unroll
    for (int o = 32; o > 0; o >>= 1) s += __shfl_xor(s, o, 64);
    if ((tid & 63) == 0) wsum[tid >> 6] = s;
    __syncthreads();
    s = wsum[0] + wsum[1] + wsum[2] + wsum[3];

    const float inv = 1.f / s;
#pragma unroll
    for (int j = 0; j < 8; ++j) f[j] = f[j] * inv;

    float4 a, b;
    a.x = f[0]; a.y = f[1]; a.z = f[2]; a.w = f[3];
    b.x = f[4]; b.y = f[5]; b.z = f[6]; b.w = f[7];
    ((float4*)pf)[2 * tid]     = a;
    ((float4*)pf)[2 * tid + 1] = b;
    ((s16x8*)p16)[tid] = cvt8h(a, b);
}

extern "C" void kernel_launch(void* const* d_in, const int* in_sizes, int n_in,
                              void* d_out, int out_size, void* d_ws, size_t ws_size,
                              hipStream_t stream) {
    const float* Q   = (const float*)d_in[0];
    const float* K   = (const float*)d_in[1];
    const float* V   = (const float*)d_in[2];
    const float* W_Q = (const float*)d_in[3];
    const float* W_K = (const float*)d_in[4];
    const float* W_V = (const float*)d_in[5];
    const float* W_O = (const float*)d_in[6];
    const int* masked = (const int*)d_in[7];

    float* out  = (float*)d_out;                    // [4,2048,1024]
    float* attn = out + (size_t)B_ * L_ * D_;       // [4,2048,2048]

    // ws layout (shorts): 8MB weights | qh 16.8 | kh 16.8 | vT 16.8 | attn16 33.6
    short* wq = (short*)d_ws;
    short* wk = wq + (size_t)D_ * D_;
    short* wv = wk + (size_t)D_ * D_;
    short* wo = wv + (size_t)D_ * D_;
    short* qh = wo + (size_t)D_ * D_;               // [8192,1024] f16
    short* kh = qh + (size_t)B_ * L_ * D_;
    short* vT = kh + (size_t)B_ * L_ * D_;          // [4][1024][2048] f16
    short* attn16 = vT + (size_t)B_ * L_ * D_;      // [4][2048][2048] f16
    short* xh = qh;                                 // reuse after scores

    // fp16 Q/K/V copies live in d_out's attn region (dead before softmax writes it)
    short* qf = (short*)attn;                       // 3 x 16.8 MB <= 67 MB
    short* kf = qf + (size_t)B_ * L_ * D_;
    short* vf = kf + (size_t)B_ * L_ * D_;

    const long SLD = (long)L_ * D_;
    const long SLL = (long)L_ * L_;

    // 1) weights + inputs fp32 -> fp16
    cvt_w4_k<<<dim3(D_ * D_ / 8 / 256, 4), 256, 0, stream>>>(W_Q, W_K, W_V, W_O, wq);
    cvt_qkv_k<<<dim3(B_ * L_ * D_ / 8 / 256, 3), 256, 0, stream>>>(Q, K, V, qf);

    // 2) fused QKV projections: BK=64 2-phase, 1536 blocks = 3 full rounds at 2/CU
    hgemm64_proj<<<dim3(8, 64, 3), 256, 0, stream>>>(
        qf, kf, vf, wq, wk, wv, qh, kh, vT);

    // 3) scores = q @ k^T / 8 -> f16 UNNORMALIZED into attn16 (+ faithful mask)
    hgemm8_scores<<<dim3(8, 8, B_), 512, 0, stream>>>(qh, kh, attn16, masked);

    // 4) softmax rows: read f16 scores, write fp32 attn + normalized f16 in place
    softmax_rows_k<<<dim3(B_ * L_), 256, 0, stream>>>(attn16, attn);

    // 5) x = attn16 @ vT -> f16 x : BK=64 2-phase, 512 blocks = 1 round at 2/CU
    hgemm64_pipe<0><<<dim3(8, 16, B_), 256, 0, stream>>>(
        attn16, vT, xh, D_, L_, SLL, SLD, SLD);

    // 6) out = x @ W_O^T -> fp32 : BK=64 2-phase, 512 blocks
    hgemm64_pipe<2><<<dim3(8, 64, 1), 256, 0, stream>>>(
        xh, wo, out, D_, D_, 0, 0, 0);
}

// Round 19
// 217.719 us; speedup vs baseline: 1.1098x; 1.0059x over previous
//
#include <hip/hip_runtime.h>
#include <math.h>

// MaskedMultiHeadAttention (B=4, L=2048, D=1024), fp32 in/out, fp16-MFMA internals.
// d_out = [ out : 4*2048*1024 f32 | attn : 4*2048*2048 f32 ]
// ws (92MB): wq wk wv wo (f16) | qh | kh | vT | attn16 (f16); x reuses qh.
// Round 19 = round 18 (219us) + coalesced epilogues:
//   - vT (proj z=2): transposed LDS-bounce -> 16B contiguous stores along m
//     (was u16x4 at 4KB stride);
//   - fp32 out (OMODE 2): LDS-bounce in two 32-row halves -> 2x float4/lane
//     contiguous (was scalar 4B scattered).
// All GEMMs: BK=64 2-phase counted pipeline; scores: 8-wave 256^2 quad pipeline.

static constexpr int B_ = 4;
static constexpr int L_ = 2048;
static constexpr int D_ = 1024;

typedef _Float16 f16x8 __attribute__((ext_vector_type(8)));
typedef float    f32x4 __attribute__((ext_vector_type(4)));
typedef short    s16x8 __attribute__((ext_vector_type(8)));
typedef unsigned short u16x4 __attribute__((ext_vector_type(4)));

typedef __attribute__((address_space(1))) const unsigned int GU32;
typedef __attribute__((address_space(3))) unsigned int LU32;

__device__ __forceinline__ void gload_lds16(const void* g, void* l) {
    __builtin_amdgcn_global_load_lds((GU32*)g, (LU32*)l, 16, 0, 0);
}

__device__ __forceinline__ short f2h_bits(float x) {
    union { _Float16 h; short s; } u;
    u.h = (_Float16)x;
    return u.s;
}

__device__ __forceinline__ s16x8 cvt8h(float4 a, float4 b) {
    union { _Float16 h[8]; s16x8 s; } u;
    u.h[0] = (_Float16)a.x; u.h[1] = (_Float16)a.y;
    u.h[2] = (_Float16)a.z; u.h[3] = (_Float16)a.w;
    u.h[4] = (_Float16)b.x; u.h[5] = (_Float16)b.y;
    u.h[6] = (_Float16)b.z; u.h[7] = (_Float16)b.w;
    return u.s;
}

// ================= shared classic-geometry pieces =================

// One BK=64 step: 2 k-subtiles x (8 ds_read_b128 + 16 MFMA) per wave.
__device__ __forceinline__ void compute_step(
    const short* __restrict__ As, const short* __restrict__ Bs,
    int wr, int wc, int lr, int lk, f32x4 (&acc)[4][4])
{
#pragma unroll
    for (int kk = 0; kk < 2; ++kk) {
        const int slotk = kk * 4 + lk;
        f16x8 a[4], b[4];
#pragma unroll
        for (int m = 0; m < 4; ++m) {
            const int r = wr * 64 + m * 16 + lr;
            a[m] = *(const f16x8*)&As[r * 64 + ((slotk ^ (r & 7)) << 3)];
        }
#pragma unroll
        for (int n = 0; n < 4; ++n) {
            const int c = wc * 64 + n * 16 + lr;
            b[n] = *(const f16x8*)&Bs[c * 64 + ((slotk ^ (c & 7)) << 3)];
        }
        __builtin_amdgcn_s_setprio(1);
#pragma unroll
        for (int m = 0; m < 4; ++m)
#pragma unroll
            for (int n = 0; n < 4; ++n)
                acc[m][n] = __builtin_amdgcn_mfma_f32_16x16x32_f16(a[m], b[n], acc[m][n], 0, 0, 0);
        __builtin_amdgcn_s_setprio(0);
    }
}

// Classic BKK=64 staging of one 128x64 tile pair into a given buffer.
__device__ __forceinline__ void stage64(
    const short* __restrict__ A16, const short* __restrict__ Bt,
    short* __restrict__ As, short* __restrict__ Bs,
    int bm, int bn, int k0, int K, int srow, int sslot, int wid)
{
#pragma unroll
    for (int i = 0; i < 4; ++i) {
        const int rb = i * 32 + srow;
        const short* g = Bt + (long)(bn + rb) * K + k0 + ((sslot ^ (rb & 7)) << 3);
        gload_lds16(g, &Bs[i * 2048 + wid * 512]);
    }
#pragma unroll
    for (int i = 0; i < 4; ++i) {
        const int ra = i * 32 + srow;
        const short* g = A16 + (long)(bm + ra) * K + k0 + ((sslot ^ (ra & 7)) << 3);
        gload_lds16(g, &As[i * 2048 + wid * 512]);
    }
}

// wave 64x64 f16 LDS-bounce epilogue (4096-short wave region), row-major C.
template<int APPLY_SM>
__device__ __forceinline__ void epilogue_f16_bounce(
    short* __restrict__ lw, short* __restrict__ C, long N,
    int bm, int bn, int wr, int wc, int lr, int lk, int lane,
    const f32x4 (&acc)[4][4], float scale, bool msk)
{
#pragma unroll
    for (int m = 0; m < 4; ++m) {
        const int rl0 = m * 16 + lk * 4;
#pragma unroll
        for (int n = 0; n < 4; ++n) {
            const int cl = n * 16 + lr;
            const int slot = cl >> 3, cw = cl & 7;
#pragma unroll
            for (int g = 0; g < 4; ++g) {
                const int rl = rl0 + g;
                float v = acc[m][n][g];
                if constexpr (APPLY_SM) {
                    v *= scale;
                    if (msk && (bn + wc * 64 + cl) <= (bm + wr * 64 + rl)) v = -INFINITY;
                }
                lw[rl * 64 + ((slot ^ (rl & 7)) << 3) + cw] = f2h_bits(v);
            }
        }
    }
    const int l8 = lane & 7, lr8 = lane >> 3;
#pragma unroll
    for (int it = 0; it < 8; ++it) {
        const int rl = it * 8 + lr8;
        const int cl = (l8 ^ (rl & 7)) << 3;
        s16x8 d = *(const s16x8*)&lw[rl * 64 + (l8 << 3)];
        *(s16x8*)&C[(long)(bm + wr * 64 + rl) * N + bn + wc * 64 + cl] = d;
    }
}

// TRANSPOSED f16 bounce: C indexed [col][row] (vT layout). LDS holds the tile
// as [cl][swizzled rl-slot]; readback is 16B contiguous along the row dim.
__device__ __forceinline__ void epilogue_f16_bounce_T(
    short* __restrict__ lw, short* __restrict__ vT,
    int rowBase /*global m base*/, int colBase /*global n base*/,
    int lr, int lk, int lane, const f32x4 (&acc)[4][4])
{
#pragma unroll
    for (int m = 0; m < 4; ++m) {
        const int rl0 = m * 16 + lk * 4;
#pragma unroll
        for (int n = 0; n < 4; ++n) {
            const int cl = n * 16 + lr;
#pragma unroll
            for (int g = 0; g < 4; ++g) {
                const int rl = rl0 + g;
                const int slot = rl >> 3, cw = rl & 7;
                lw[cl * 64 + ((slot ^ (cl & 7)) << 3) + cw] = f2h_bits(acc[m][n][g]);
            }
        }
    }
    // batch from global m (tile never straddles batch: rowBase 64-aligned < 2048k)
    const long bb = (long)(rowBase >> 11) * ((long)D_ * L_);
    const int rbase = rowBase & (L_ - 1);
    const int l8 = lane & 7, lr8 = lane >> 3;
#pragma unroll
    for (int it = 0; it < 8; ++it) {
        const int nl = it * 8 + lr8;                 // local col (n)
        const int cm = (l8 ^ (nl & 7)) << 3;         // logical m-slot of phys l8
        s16x8 d = *(const s16x8*)&lw[nl * 64 + (l8 << 3)];
        *(s16x8*)&vT[bb + (long)(colBase + nl) * L_ + rbase + cm] = d;
    }
}

// fp32 bounce: C row-major [M,N] fp32, via two 32-row halves of the 8KB region.
__device__ __forceinline__ void epilogue_f32_bounce(
    short* __restrict__ lw_, float* __restrict__ C, long N,
    int rowBase, int colBase, int lr, int lk, int lane,
    const f32x4 (&acc)[4][4])
{
    float* lwf = (float*)lw_;   // 2048 floats = 32 x 64
    const int l8 = lane & 7, lr8 = lane >> 3;
#pragma unroll
    for (int h = 0; h < 2; ++h) {
#pragma unroll
        for (int mm = 0; mm < 2; ++mm) {
            const int m = h * 2 + mm;
            const int rl0 = mm * 16 + lk * 4;        // 0..31 within half
#pragma unroll
            for (int n = 0; n < 4; ++n) {
                const int cl = n * 16 + lr;
                const int slot = cl >> 3, cw = cl & 7;
#pragma unroll
                for (int g = 0; g < 4; ++g) {
                    const int rl = rl0 + g;
                    lwf[rl * 64 + ((slot ^ (rl & 7)) << 3) + cw] = acc[m][n][g];
                }
            }
        }
        // readback: 4 iters x 8 rows; lane reads 8 floats (one 32B slot)
#pragma unroll
        for (int it = 0; it < 4; ++it) {
            const int rl = it * 8 + lr8;
            const int cl = (l8 ^ (rl & 7)) << 3;
            const float* src = &lwf[rl * 64 + (l8 << 3)];
            float4 v0 = *(const float4*)&src[0];
            float4 v1 = *(const float4*)&src[4];
            float* dst = &C[(long)(rowBase + h * 32 + rl) * N + colBase + cl];
            *(float4*)&dst[0] = v0;
            *(float4*)&dst[4] = v1;
        }
    }
}

// 2-phase double-buffered BK=64 K-loop: gate vmcnt(0) lands one full compute
// phase after the loads were issued; stage(t+1) issued after the barrier.
__device__ __forceinline__ void pipeline2_64(
    const short* __restrict__ A16, const short* __restrict__ Bt,
    short* __restrict__ smem,
    int bm, int bn, int K, int srow, int sslot, int wid,
    int wr, int wc, int lr, int lk, f32x4 (&acc)[4][4])
{
    // buffer b: smem + b*16384 shorts; layout A[8192] | B[8192] (32KB each)
    stage64(A16, Bt, smem, smem + 8192, bm, bn, 0, K, srow, sslot, wid);

    const int nt = K / 64;
    for (int ti = 0; ti < nt; ++ti) {
        asm volatile("s_waitcnt vmcnt(0)" ::: "memory");
        __builtin_amdgcn_sched_barrier(0);
        __builtin_amdgcn_s_barrier();
        __builtin_amdgcn_sched_barrier(0);
        const int cur = (ti & 1) * 16384;
        if (ti + 1 < nt) {
            const int nxt = ((ti + 1) & 1) * 16384;
            stage64(A16, Bt, smem + nxt, smem + nxt + 8192, bm, bn,
                    (ti + 1) * 64, K, srow, sslot, wid);
        }
        compute_step(smem + cur, smem + cur + 8192, wr, wc, lr, lk, acc);
    }
    __syncthreads();   // all buffer reads done before LDS reuse by epilogue
}

// generic pipelined GEMM, 128x128 tile. OMODE: 0 = f16 [M,N]; 2 = f32 [M,N].
template<int OMODE>
__global__ __launch_bounds__(256) void hgemm64_pipe(
    const short* __restrict__ A16p, const short* __restrict__ Btp, void* __restrict__ Cp_,
    int N, int K, long sA, long sB, long sC)
{
    __shared__ short smem[32768];   // 64 KB

    const int t    = threadIdx.x;
    const int wid  = t >> 6;
    const int lane = t & 63;
    const int bz   = blockIdx.z;

    const int gx = gridDim.x, gy = gridDim.y;
    const int wg = blockIdx.y * gx + blockIdx.x;
    const int bm = (wg % gy) * 128;   // M-panel pinned to one XCD (gy%8==0)
    const int bn = (wg / gy) * 128;

    const short* A16 = A16p + (long)bz * sA;
    const short* Bt  = Btp + (long)bz * sB;

    const int wr = wid >> 1, wc = wid & 1;
    const int lr = lane & 15, lk = lane >> 4;
    const int srow = t >> 3, sslot = t & 7;

    f32x4 acc[4][4];
#pragma unroll
    for (int m = 0; m < 4; ++m)
#pragma unroll
        for (int n = 0; n < 4; ++n) acc[m][n] = (f32x4)0.f;

    pipeline2_64(A16, Bt, smem, bm, bn, K, srow, sslot, wid, wr, wc, lr, lk, acc);

    if constexpr (OMODE == 2) {
        float* C = (float*)Cp_ + (long)bz * sC;
        epilogue_f32_bounce(smem + wid * 4096, C, N,
                            bm + wr * 64, bn + wc * 64, lr, lk, lane, acc);
    } else {
        short* C = (short*)Cp_ + (long)bz * sC;
        epilogue_f16_bounce<0>(smem + wid * 4096, C, N, bm, bn, wr, wc, lr, lk, lane,
                               acc, 1.f, false);
    }
}

// fused QKV projections, 2-phase pipeline. grid (8, 64, 3), 256 threads.
__global__ __launch_bounds__(256) void hgemm64_proj(
    const short* __restrict__ qf, const short* __restrict__ kf, const short* __restrict__ vf,
    const short* __restrict__ wq, const short* __restrict__ wk, const short* __restrict__ wv,
    short* __restrict__ qh, short* __restrict__ kh, short* __restrict__ vT)
{
    __shared__ short smem[32768];   // 64 KB

    const int t    = threadIdx.x;
    const int wid  = t >> 6;
    const int lane = t & 63;
    const int bz   = blockIdx.z;
    const int K    = D_;
    const int N    = D_;

    const short* A16 = (bz == 0) ? qf : (bz == 1) ? kf : vf;
    const short* Bt  = (bz == 0) ? wq : (bz == 1) ? wk : wv;

    const int gx = gridDim.x, gy = gridDim.y;
    const int wg = blockIdx.y * gx + blockIdx.x;
    const int bm = (wg % gy) * 128;
    const int bn = (wg / gy) * 128;

    const int wr = wid >> 1, wc = wid & 1;
    const int lr = lane & 15, lk = lane >> 4;
    const int srow = t >> 3, sslot = t & 7;

    f32x4 acc[4][4];
#pragma unroll
    for (int m = 0; m < 4; ++m)
#pragma unroll
        for (int n = 0; n < 4; ++n) acc[m][n] = (f32x4)0.f;

    pipeline2_64(A16, Bt, smem, bm, bn, K, srow, sslot, wid, wr, wc, lr, lk, acc);

    if (bz < 2) {
        short* C = (bz == 0) ? qh : kh;
        epilogue_f16_bounce<0>(smem + wid * 4096, C, N, bm, bn, wr, wc, lr, lk, lane,
                               acc, 1.f, false);
    } else {
        epilogue_f16_bounce_T(smem + wid * 4096, vT,
                              bm + wr * 64, bn + wc * 64, lr, lk, lane, acc);
    }
}

// ============== 8-wave 256x256 quad pipeline (round-12 proven, scores) ==============

__device__ __forceinline__ void stage8(
    const short* __restrict__ A16, const short* __restrict__ Bt,
    short* __restrict__ As, short* __restrict__ Bs,
    int bm, int bn, int k0, int K, int t, int wid)
{
    const int r0 = t >> 2;
    const int sl = t & 3;
#pragma unroll
    for (int i = 0; i < 2; ++i) {
        const int r = i * 128 + r0;
        const short* g = A16 + (long)(bm + r) * K + k0 + ((sl ^ ((r >> 1) & 3)) << 3);
        gload_lds16(g, As + i * 4096 + wid * 512);
    }
#pragma unroll
    for (int i = 0; i < 2; ++i) {
        const int r = i * 128 + r0;
        const short* g = Bt + (long)(bn + r) * K + k0 + ((sl ^ ((r >> 1) & 3)) << 3);
        gload_lds16(g, Bs + i * 4096 + wid * 512);
    }
}

__device__ __forceinline__ void compute32_w8(
    const short* __restrict__ As, const short* __restrict__ Bs,
    int wr, int wc, int lr, int lk, f32x4 (&acc)[8][4])
{
    f16x8 a[8], b[4];
#pragma unroll
    for (int m = 0; m < 8; ++m) {
        const int r = wr * 128 + m * 16 + lr;
        a[m] = *(const f16x8*)&As[r * 32 + ((lk ^ ((r >> 1) & 3)) << 3)];
    }
#pragma unroll
    for (int n = 0; n < 4; ++n) {
        const int c = wc * 64 + n * 16 + lr;
        b[n] = *(const f16x8*)&Bs[c * 32 + ((lk ^ ((c >> 1) & 3)) << 3)];
    }
    __builtin_amdgcn_s_setprio(1);
#pragma unroll
    for (int m = 0; m < 8; ++m)
#pragma unroll
        for (int n = 0; n < 4; ++n)
            acc[m][n] = __builtin_amdgcn_mfma_f32_16x16x32_f16(a[m], b[n], acc[m][n], 0, 0, 0);
    __builtin_amdgcn_s_setprio(0);
}

template<int APPLY_SM>
__device__ __forceinline__ void epilogue_f16_bounce8(
    short* __restrict__ lw, short* __restrict__ C, long N,
    int rowBase, int colBase, int lr, int lk, int lane,
    const f32x4 (&acc)[8][4], float scale, bool msk)
{
#pragma unroll
    for (int h = 0; h < 2; ++h) {
#pragma unroll
        for (int mm = 0; mm < 4; ++mm) {
            const int m = h * 4 + mm;
            const int rl0 = mm * 16 + lk * 4;
#pragma unroll
            for (int n = 0; n < 4; ++n) {
                const int cl = n * 16 + lr;
                const int slot = cl >> 3, cw = cl & 7;
#pragma unroll
                for (int g = 0; g < 4; ++g) {
                    const int rl = rl0 + g;
                    float v = acc[m][n][g];
                    if constexpr (APPLY_SM) {
                        v *= scale;
                        if (msk && (colBase + cl) <= (rowBase + h * 64 + rl)) v = -INFINITY;
                    }
                    lw[rl * 64 + ((slot ^ (rl & 7)) << 3) + cw] = f2h_bits(v);
                }
            }
        }
        const int l8 = lane & 7, lr8 = lane >> 3;
#pragma unroll
        for (int it = 0; it < 8; ++it) {
            const int rl = it * 8 + lr8;
            const int cl = (l8 ^ (rl & 7)) << 3;
            s16x8 d = *(const s16x8*)&lw[rl * 64 + (l8 << 3)];
            *(s16x8*)&C[(long)(rowBase + h * 64 + rl) * N + colBase + cl] = d;
        }
    }
}

__device__ __forceinline__ void pipeline_loop8(
    const short* __restrict__ A16, const short* __restrict__ Bt,
    short* __restrict__ Abuf, short* __restrict__ Bbuf,
    int bm, int bn, int K, int t, int wid,
    int wr, int wc, int lr, int lk, f32x4 (&acc)[8][4])
{
    stage8(A16, Bt, Abuf + 0 * 8192, Bbuf + 0 * 8192, bm, bn, 0,  K, t, wid);
    stage8(A16, Bt, Abuf + 1 * 8192, Bbuf + 1 * 8192, bm, bn, 32, K, t, wid);
    stage8(A16, Bt, Abuf + 2 * 8192, Bbuf + 2 * 8192, bm, bn, 64, K, t, wid);

    const int nt = K / 32;
    for (int ti = 0; ti < nt; ++ti) {
        if (ti + 2 < nt)      asm volatile("s_waitcnt vmcnt(8)" ::: "memory");
        else if (ti + 1 < nt) asm volatile("s_waitcnt vmcnt(4)" ::: "memory");
        else                  asm volatile("s_waitcnt vmcnt(0)" ::: "memory");
        __builtin_amdgcn_sched_barrier(0);
        __builtin_amdgcn_s_barrier();
        __builtin_amdgcn_sched_barrier(0);
        asm volatile("" ::: "memory");
        if (ti + 3 < nt) {
            const int nb = (ti + 3) & 3;
            stage8(A16, Bt, Abuf + nb * 8192, Bbuf + nb * 8192, bm, bn,
                   (ti + 3) * 32, K, t, wid);
        }
        const int cb = ti & 3;
        compute32_w8(Abuf + cb * 8192, Bbuf + cb * 8192, wr, wc, lr, lk, acc);
    }
    __syncthreads();
}

// scores = qh @ kh^T * 0.125 -> f16 attn16 (+ faithful-buggy tril mask)
__global__ __launch_bounds__(512) void hgemm8_scores(
    const short* __restrict__ qhp, const short* __restrict__ khp,
    short* __restrict__ Cp, const int* __restrict__ mflag)
{
    __shared__ short smem[65536];

    const int t    = threadIdx.x;
    const int wid  = t >> 6;
    const int lane = t & 63;
    const int bz   = blockIdx.z;
    const int K    = D_;

    const int wg = blockIdx.y * 8 + blockIdx.x;
    const int bm = (wg % 8) * 256;
    const int bn = (wg / 8) * 256;

    const short* A16 = qhp + (long)bz * L_ * D_;
    const short* Bt  = khp + (long)bz * L_ * D_;
    short* C = Cp + (long)bz * ((long)L_ * L_);

    const int wr = wid >> 2, wc = wid & 3;
    const int lr = lane & 15, lk = lane >> 4;

    f32x4 acc[8][4];
#pragma unroll
    for (int m = 0; m < 8; ++m)
#pragma unroll
        for (int n = 0; n < 4; ++n) acc[m][n] = (f32x4)0.f;

    pipeline_loop8(A16, Bt, smem, smem + 32768, bm, bn, K, t, wid, wr, wc, lr, lk, acc);

    const bool msk = (mflag[0] != 0);
    epilogue_f16_bounce8<1>(smem + wid * 4096, C, L_,
                            bm + wr * 128, bn + wc * 64, lr, lk, lane,
                            acc, 0.125f, msk);
}

// ================= small kernels (proven) =================

__global__ __launch_bounds__(256) void cvt_w4_k(
    const float* __restrict__ W_Q, const float* __restrict__ W_K,
    const float* __restrict__ W_V, const float* __restrict__ W_O,
    short* __restrict__ dst)
{
    const int w = blockIdx.y;
    const float* src = (w == 0) ? W_Q : (w == 1) ? W_K : (w == 2) ? W_V : W_O;
    short* out = dst + (size_t)w * D_ * D_;
    const int i = blockIdx.x * 256 + threadIdx.x;
    float4 a = ((const float4*)src)[2 * i];
    float4 b = ((const float4*)src)[2 * i + 1];
    *(s16x8*)&out[i * 8] = cvt8h(a, b);
}

__global__ __launch_bounds__(256) void cvt_qkv_k(
    const float* __restrict__ Q, const float* __restrict__ K,
    const float* __restrict__ V, short* __restrict__ dst)
{
    const int w = blockIdx.y;
    const float* src = (w == 0) ? Q : (w == 1) ? K : V;
    short* out = dst + (size_t)w * B_ * L_ * D_;
    const int i = blockIdx.x * 256 + threadIdx.x;
    float4 a = ((const float4*)src)[2 * i];
    float4 b = ((const float4*)src)[2 * i + 1];
    *(s16x8*)&out[i * 8] = cvt8h(a, b);
}

// row softmax over f16 unnormalized scores (rows of 2048):
// writes fp32 normalized attn (d_out) + f16 normalized copy in place.
__global__ __launch_bounds__(256) void softmax_rows_k(
    short* __restrict__ S16, float* __restrict__ Sout)
{
    const long row = blockIdx.x;
    short* p16 = S16 + row * (long)L_;
    float* pf  = Sout + row * (long)L_;
    const int tid = threadIdx.x;

    union { s16x8 v; _Float16 h[8]; } u;
    u.v = ((const s16x8*)p16)[tid];
    float f[8];
#pragma unroll
    for (int j = 0; j < 8; ++j) f[j] = (float)u.h[j];

    float m = f[0];
#pragma unroll
    for (int j = 1; j < 8; ++j) m = fmaxf(m, f[j]);
#pragma unroll
    for (int o = 32; o > 0; o >>= 1) m = fmaxf(m, __shfl_xor(m, o, 64));

    __shared__ float wmax[4], wsum[4];
    if ((tid & 63) == 0) wmax[tid >> 6] = m;
    __syncthreads();
    m = fmaxf(fmaxf(wmax[0], wmax[1]), fmaxf(wmax[2], wmax[3]));

    float s = 0.f;
#pragma unroll
    for (int j = 0; j < 8; ++j) { f[j] = expf(f[j] - m); s += f[j]; }
#pragma unroll
    for (int o = 32; o > 0; o >>= 1) s += __shfl_xor(s, o, 64);
    if ((tid & 63) == 0) wsum[tid >> 6] = s;
    __syncthreads();
    s = wsum[0] + wsum[1] + wsum[2] + wsum[3];

    const float inv = 1.f / s;
#pragma unroll
    for (int j = 0; j < 8; ++j) f[j] = f[j] * inv;

    float4 a, b;
    a.x = f[0]; a.y = f[1]; a.z = f[2]; a.w = f[3];
    b.x = f[4]; b.y = f[5]; b.z = f[6]; b.w = f[7];
    ((float4*)pf)[2 * tid]     = a;
    ((float4*)pf)[2 * tid + 1] = b;
    ((s16x8*)p16)[tid] = cvt8h(a, b);
}

extern "C" void kernel_launch(void* const* d_in, const int* in_sizes, int n_in,
                              void* d_out, int out_size, void* d_ws, size_t ws_size,
                              hipStream_t stream) {
    const float* Q   = (const float*)d_in[0];
    const float* K   = (const float*)d_in[1];
    const float* V   = (const float*)d_in[2];
    const float* W_Q = (const float*)d_in[3];
    const float* W_K = (const float*)d_in[4];
    const float* W_V = (const float*)d_in[5];
    const float* W_O = (const float*)d_in[6];
    const int* masked = (const int*)d_in[7];

    float* out  = (float*)d_out;                    // [4,2048,1024]
    float* attn = out + (size_t)B_ * L_ * D_;       // [4,2048,2048]

    // ws layout (shorts): 8MB weights | qh 16.8 | kh 16.8 | vT 16.8 | attn16 33.6
    short* wq = (short*)d_ws;
    short* wk = wq + (size_t)D_ * D_;
    short* wv = wk + (size_t)D_ * D_;
    short* wo = wv + (size_t)D_ * D_;
    short* qh = wo + (size_t)D_ * D_;               // [8192,1024] f16
    short* kh = qh + (size_t)B_ * L_ * D_;
    short* vT = kh + (size_t)B_ * L_ * D_;          // [4][1024][2048] f16
    short* attn16 = vT + (size_t)B_ * L_ * D_;      // [4][2048][2048] f16
    short* xh = qh;                                 // reuse after scores

    // fp16 Q/K/V copies live in d_out's attn region (dead before softmax writes it)
    short* qf = (short*)attn;                       // 3 x 16.8 MB <= 67 MB
    short* kf = qf + (size_t)B_ * L_ * D_;
    short* vf = kf + (size_t)B_ * L_ * D_;

    const long SLD = (long)L_ * D_;
    const long SLL = (long)L_ * L_;

    // 1) weights + inputs fp32 -> fp16
    cvt_w4_k<<<dim3(D_ * D_ / 8 / 256, 4), 256, 0, stream>>>(W_Q, W_K, W_V, W_O, wq);
    cvt_qkv_k<<<dim3(B_ * L_ * D_ / 8 / 256, 3), 256, 0, stream>>>(Q, K, V, qf);

    // 2) fused QKV projections: BK=64 2-phase, 1536 blocks = 3 full rounds at 2/CU
    hgemm64_proj<<<dim3(8, 64, 3), 256, 0, stream>>>(
        qf, kf, vf, wq, wk, wv, qh, kh, vT);

    // 3) scores = q @ k^T / 8 -> f16 UNNORMALIZED into attn16 (+ faithful mask)
    hgemm8_scores<<<dim3(8, 8, B_), 512, 0, stream>>>(qh, kh, attn16, masked);

    // 4) softmax rows: read f16 scores, write fp32 attn + normalized f16 in place
    softmax_rows_k<<<dim3(B_ * L_), 256, 0, stream>>>(attn16, attn);

    // 5) x = attn16 @ vT -> f16 x : BK=64 2-phase, 512 blocks = 1 round at 2/CU
    hgemm64_pipe<0><<<dim3(8, 16, B_), 256, 0, stream>>>(
        attn16, vT, xh, D_, L_, SLL, SLD, SLD);

    // 6) out = x @ W_O^T -> fp32 : BK=64 2-phase, 512 blocks
    hgemm64_pipe<2><<<dim3(8, 64, 1), 256, 0, stream>>>(
        xh, wo, out, D_, D_, 0, 0, 0);
}